// Round 6
// baseline (608.750 us; speedup 1.0000x reference)
//
#include <hip/hip_runtime.h>
#include <cstdint>
#include <cstddef>

#define NN 8192
#define EE 262144
#define ET 270336   // EE + NN self loops

using short8  = __attribute__((ext_vector_type(8))) short;
using floatx4 = __attribute__((ext_vector_type(4))) float;

__device__ __forceinline__ unsigned short f2bf(float f) {
  unsigned int u = __float_as_uint(f);
  u += 0x7fffu + ((u >> 16) & 1u);          // RNE
  return (unsigned short)(u >> 16);
}

// ---------------- CSR build, both graphs in one launch ----------------
__global__ void edge_hist2_k(const int* __restrict__ ei_t, const int* __restrict__ ei_e,
                             int* __restrict__ cnt_t, int* __restrict__ cnt_e) {
  int idx = blockIdx.x * 256 + threadIdx.x;
  int g = idx >= ET;                        // block-uniform (ET % 256 == 0)
  int e = g ? idx - ET : idx;
  const int* ei = g ? ei_e : ei_t;
  int* cnt = g ? cnt_e : cnt_t;
  int d = (e < EE) ? ei[EE + e] : (e - EE);
  atomicAdd(&cnt[d], 1);
}

__global__ void scan2_k(int* cnt_t, int* off_t, int* cnt_e, int* off_e) {
  int* cnt = blockIdx.x ? cnt_e : cnt_t;    // pos aliases cnt (overwritten)
  int* off = blockIdx.x ? off_e : off_t;
  __shared__ int s[1024];
  int t = threadIdx.x;
  int v[8]; int base = t * 8; int sum = 0;
  #pragma unroll
  for (int j = 0; j < 8; ++j) { v[j] = cnt[base + j]; sum += v[j]; }
  s[t] = sum; __syncthreads();
  for (int o = 1; o < 1024; o <<= 1) {
    int x = (t >= o) ? s[t - o] : 0;
    __syncthreads();
    s[t] += x;
    __syncthreads();
  }
  int excl = s[t] - sum;
  #pragma unroll
  for (int j = 0; j < 8; ++j) { off[base + j] = excl; cnt[base + j] = excl; excl += v[j]; }
  if (t == 1023) off[NN] = excl;
}

__global__ void edge_scatter2_k(const int* __restrict__ ei_t, const int* __restrict__ ei_e,
                                int* __restrict__ pos_t, int* __restrict__ pos_e,
                                int* __restrict__ srcs_t, int* __restrict__ srcs_e) {
  int idx = blockIdx.x * 256 + threadIdx.x;
  int g = idx >= ET;
  int e = g ? idx - ET : idx;
  const int* ei = g ? ei_e : ei_t;
  int* pos = g ? pos_e : pos_t;
  int* srcs = g ? srcs_e : srcs_t;
  int sv, d;
  if (e < EE) { sv = ei[e]; d = ei[EE + e]; } else { sv = d = e - EE; }
  int p = atomicAdd(&pos[d], 1);
  srcs[p] = sv;
}

// ---------------- shared GEMM inner loop ----------------
__device__ __forceinline__ void gemm_core(const float* __restrict__ A, int lda, int K,
                                          const float* __restrict__ Bs, int row0, int col,
                                          float acc[8]) {
  #pragma unroll
  for (int r = 0; r < 8; ++r) acc[r] = 0.f;
  for (int k = 0; k < K; k += 4) {
    float b0 = Bs[(k + 0) * 32 + col], b1 = Bs[(k + 1) * 32 + col];
    float b2 = Bs[(k + 2) * 32 + col], b3 = Bs[(k + 3) * 32 + col];
    #pragma unroll
    for (int r = 0; r < 8; ++r) {
      const float4 a4 = *(const float4*)(A + (size_t)(row0 + r) * lda + k);
      acc[r] = fmaf(a4.x, b0, acc[r]);
      acc[r] = fmaf(a4.y, b1, acc[r]);
      acc[r] = fmaf(a4.z, b2, acc[r]);
      acc[r] = fmaf(a4.w, b3, acc[r]);
    }
  }
}

// ---------------- mm_x: h1 = x@gat1_W (+att_sd epilogue), hg1 = x@gcn1_W ----------------
__global__ __launch_bounds__(256) void mm_x_k(const float* __restrict__ x,
    const float* __restrict__ Wgat, const float* __restrict__ Wgcn,
    const float* __restrict__ as_w, const float* __restrict__ ad_w,
    float* __restrict__ h1, float* __restrict__ hg1,
    float* __restrict__ a_s1, float* __restrict__ a_d1) {
  __shared__ float Bs[256 * 32];
  const int tid = threadIdx.x, by = blockIdx.y;
  const bool gat = by < 4;
  const int NC = gat ? 128 : 64;
  const int c0 = gat ? by * 32 : (by - 4) * 32;
  const float* B = gat ? Wgat : Wgcn;
  for (int idx = tid; idx < 256 * 32; idx += 256)
    Bs[idx] = B[(idx >> 5) * NC + c0 + (idx & 31)];
  __syncthreads();
  const int row0 = blockIdx.x * 64 + (tid >> 5) * 8;
  const int col = tid & 31;
  float acc[8];
  gemm_core(x, 256, 256, Bs, row0, col, acc);
  if (gat) {
    #pragma unroll
    for (int r = 0; r < 8; ++r) h1[(size_t)(row0 + r) * 128 + c0 + col] = acc[r];
    const int head = c0 >> 6;
    const float asw = as_w[head * 64 + (c0 & 63) + col];
    const float adw = ad_w[head * 64 + (c0 & 63) + col];
    float ps[8], pd[8];
    #pragma unroll
    for (int r = 0; r < 8; ++r) { ps[r] = acc[r] * asw; pd[r] = acc[r] * adw; }
    #pragma unroll
    for (int m = 16; m >= 1; m >>= 1)
      #pragma unroll
      for (int r = 0; r < 8; ++r) { ps[r] += __shfl_xor(ps[r], m); pd[r] += __shfl_xor(pd[r], m); }
    if (col == 0) {
      #pragma unroll
      for (int r = 0; r < 8; ++r) {
        atomicAdd(&a_s1[(row0 + r) * 2 + head], ps[r]);
        atomicAdd(&a_d1[(row0 + r) * 2 + head], pd[r]);
      }
    }
  } else {
    #pragma unroll
    for (int r = 0; r < 8; ++r) hg1[(size_t)(row0 + r) * 64 + c0 + col] = acc[r];
  }
}

// ---------------- GAT aggregation ----------------
// Inner gather loop padded to x4 (zero weights) so the compiler can keep 4
// independent L2 gathers in flight (dynamic trip count otherwise blocks unroll).
template<int H, int C>
__device__ __forceinline__ void gat_agg_body(const float* __restrict__ h,
    const float* __restrict__ a_s, const float* __restrict__ a_d,
    const int* __restrict__ off, const int* __restrict__ srcs,
    const float* __restrict__ bias, float* __restrict__ out, int ldout, int b) {
  constexpr int HC = H * C;
  const int tid = threadIdx.x;
  const int hd = tid / C;
  const int r0 = off[b], r1 = off[b + 1];
  __shared__ int s_src[HC];
  __shared__ float s_w[HC][H];
  float ad[H];
  #pragma unroll
  for (int hh = 0; hh < H; ++hh) ad[hh] = a_d[b * H + hh];
  float acc = 0.f, den = 0.f;
  for (int base = r0; base < r1; base += HC) {
    const int cnt = min(HC, r1 - base);
    const int cnt4 = (cnt + 3) & ~3;
    __syncthreads();
    int e = base + tid;
    if (e < r1) {
      int sv = srcs[e];
      s_src[tid] = sv;
      #pragma unroll
      for (int hh = 0; hh < H; ++hh) {
        float xv = a_s[sv * H + hh] + ad[hh];
        xv = xv > 0.f ? xv : 0.2f * xv;     // leaky_relu 0.2
        s_w[tid][hh] = __expf(xv);
      }
    } else if (tid < cnt4) {                // zero-weight padding
      s_src[tid] = 0;
      #pragma unroll
      for (int hh = 0; hh < H; ++hh) s_w[tid][hh] = 0.f;
    }
    __syncthreads();
    for (int j = 0; j < cnt4; j += 4) {
      #pragma unroll
      for (int u = 0; u < 4; ++u) {
        float wv = s_w[j + u][hd];
        den += wv;
        acc = fmaf(wv, h[(size_t)s_src[j + u] * HC + tid], acc);
      }
    }
  }
  float o = acc / den + bias[tid];
  out[(size_t)b * ldout + tid] = o > 0.f ? o : (__expf(o) - 1.f);  // elu
}

template<int H, int C>
__global__ void gat_agg_k(const float* __restrict__ h, const float* __restrict__ a_s,
                          const float* __restrict__ a_d, const int* __restrict__ off,
                          const int* __restrict__ srcs, const float* __restrict__ bias,
                          float* __restrict__ out, int ldout) {
  gat_agg_body<H, C>(h, a_s, a_d, off, srcs, bias, out, ldout, blockIdx.x);
}

// ---------------- merged: gat1 aggregation (blocks 0..NN) + gcn1 agg+gemv (2 nodes/blk) ----
__global__ __launch_bounds__(128) void agg1_k(
    const float* __restrict__ h1, const float* __restrict__ a_s1, const float* __restrict__ a_d1,
    const int* __restrict__ off_t, const int* __restrict__ src_t,
    const float* __restrict__ gat1_b, float* __restrict__ g1out,
    const float* __restrict__ hg1, const int* __restrict__ off_e, const int* __restrict__ src_e,
    const float* __restrict__ gcn1_b, const float* __restrict__ gcn2_W, float* __restrict__ h2g) {
  const int tid = threadIdx.x;
  if (blockIdx.x < NN) {
    gat_agg_body<2, 64>(h1, a_s1, a_d1, off_t, src_t, gat1_b, g1out, 128, blockIdx.x);
  } else {
    const int nb = (blockIdx.x - NN) * 2;
    const int sub = tid >> 6, t = tid & 63;
    const int node = nb + sub;
    __shared__ int s_src2[2][64];
    __shared__ float s_nrm2[2][64];
    __shared__ float s_row2[2][64];
    const int r0 = off_e[node], r1 = off_e[node + 1];
    const int cA = off_e[nb + 1] - off_e[nb];
    const int cB = off_e[nb + 2] - off_e[nb + 1];
    const int trips = (max(cA, cB) + 63) >> 6;
    float dinv_b = rsqrtf((float)max(r1 - r0, 1));
    float acc = 0.f;
    for (int it = 0; it < trips; ++it) {
      const int cnt = min(64, r1 - (r0 + it * 64));
      const int cnt4 = (cnt + 3) & ~3;
      __syncthreads();
      int e = r0 + it * 64 + t;
      if (e < r1) {
        int sv = src_e[e];
        s_src2[sub][t] = sv;
        int ds = off_e[sv + 1] - off_e[sv];
        s_nrm2[sub][t] = dinv_b * rsqrtf((float)max(ds, 1));
      } else if (t < cnt4) {
        s_src2[sub][t] = 0;
        s_nrm2[sub][t] = 0.f;
      }
      __syncthreads();
      for (int j = 0; j < cnt4; j += 4) {
        #pragma unroll
        for (int u = 0; u < 4; ++u)
          acc = fmaf(s_nrm2[sub][j + u], hg1[(size_t)s_src2[sub][j + u] * 64 + t], acc);
      }
    }
    s_row2[sub][t] = fmaxf(acc + gcn1_b[t], 0.f);
    __syncthreads();
    float acc2 = 0.f;
    for (int k = 0; k < 64; ++k)
      acc2 = fmaf(s_row2[sub][k], gcn2_W[k * 64 + t], acc2);
    h2g[(size_t)node * 64 + t] = acc2;
  }
}

// ---------------- merged: mm_gat2 (blocks 0..256) + gcn_agg2 (4 nodes/blk) ----------------
__global__ __launch_bounds__(256) void mm2_k(
    const float* __restrict__ g1out, const float* __restrict__ gat2_W,
    const float* __restrict__ gat2_as, const float* __restrict__ gat2_ad,
    float* __restrict__ h2, float* __restrict__ a_s2, float* __restrict__ a_d2,
    const float* __restrict__ h2g, const int* __restrict__ off_e, const int* __restrict__ src_e,
    const float* __restrict__ gcn2_b, float* __restrict__ hekg) {
  const int tid = threadIdx.x;
  if (blockIdx.x < 256) {
    __shared__ float Bs[128 * 32];
    const int bx = blockIdx.x & 127;
    const int c0 = (blockIdx.x >> 7) * 32;
    for (int idx = tid; idx < 128 * 32; idx += 256)
      Bs[idx] = gat2_W[(idx >> 5) * 64 + c0 + (idx & 31)];
    __syncthreads();
    const int row0 = bx * 64 + (tid >> 5) * 8;
    const int col = tid & 31;
    float acc[8];
    gemm_core(g1out, 128, 128, Bs, row0, col, acc);
    const float asw = gat2_as[c0 + col];
    const float adw = gat2_ad[c0 + col];
    float ps[8], pd[8];
    #pragma unroll
    for (int r = 0; r < 8; ++r) {
      h2[(size_t)(row0 + r) * 64 + c0 + col] = acc[r];
      ps[r] = acc[r] * asw; pd[r] = acc[r] * adw;
    }
    #pragma unroll
    for (int m = 16; m >= 1; m >>= 1)
      #pragma unroll
      for (int r = 0; r < 8; ++r) { ps[r] += __shfl_xor(ps[r], m); pd[r] += __shfl_xor(pd[r], m); }
    if (col == 0) {
      #pragma unroll
      for (int r = 0; r < 8; ++r) {
        atomicAdd(&a_s2[row0 + r], ps[r]);
        atomicAdd(&a_d2[row0 + r], pd[r]);
      }
    }
  } else {
    const int nb = (blockIdx.x - 256) * 4;
    const int sub = tid >> 6, t = tid & 63;
    const int node = nb + sub;
    __shared__ int s_src4[4][64];
    __shared__ float s_nrm4[4][64];
    const int r0 = off_e[node], r1 = off_e[node + 1];
    int cmax = 0;
    #pragma unroll
    for (int i = 0; i < 4; ++i) cmax = max(cmax, off_e[nb + i + 1] - off_e[nb + i]);
    const int trips = (cmax + 63) >> 6;
    float dinv_b = rsqrtf((float)max(r1 - r0, 1));
    float acc = 0.f;
    for (int it = 0; it < trips; ++it) {
      const int cnt = min(64, r1 - (r0 + it * 64));
      const int cnt4 = (cnt + 3) & ~3;
      __syncthreads();
      int e = r0 + it * 64 + t;
      if (e < r1) {
        int sv = src_e[e];
        s_src4[sub][t] = sv;
        int ds = off_e[sv + 1] - off_e[sv];
        s_nrm4[sub][t] = dinv_b * rsqrtf((float)max(ds, 1));
      } else if (t < cnt4) {
        s_src4[sub][t] = 0;
        s_nrm4[sub][t] = 0.f;
      }
      __syncthreads();
      for (int j = 0; j < cnt4; j += 4) {
        #pragma unroll
        for (int u = 0; u < 4; ++u)
          acc = fmaf(s_nrm4[sub][j + u], h2g[(size_t)s_src4[sub][j + u] * 64 + t], acc);
      }
    }
    hekg[(size_t)node * 64 + t] = fmaxf(acc + gcn2_b[t], 0.f);
  }
}

// ---------------- qkv projections (+V transpose) ----------------
__global__ __launch_bounds__(256) void mm_qkv_k(const float* __restrict__ htkg,
    const float* __restrict__ hekg,
    const float* __restrict__ Wq, const float* __restrict__ bq,
    const float* __restrict__ Wk, const float* __restrict__ bk,
    const float* __restrict__ Wv, const float* __restrict__ bv,
    unsigned short* __restrict__ qb, unsigned short* __restrict__ kb,
    unsigned short* __restrict__ Vt) {
  __shared__ float Bs[64 * 32];
  __shared__ float Ts[32][65];
  const int tid = threadIdx.x, by = blockIdx.y;
  const int kind = by >> 1;
  const int c0 = (by & 1) * 32;
  const float* A = (kind == 0) ? htkg : hekg;
  const float* B = (kind == 0) ? Wq : (kind == 1) ? Wk : Wv;
  const float* bias = (kind == 0) ? bq : (kind == 1) ? bk : bv;
  for (int idx = tid; idx < 64 * 32; idx += 256)
    Bs[idx] = B[(idx >> 5) * 64 + c0 + (idx & 31)];
  __syncthreads();
  const int row0 = blockIdx.x * 64 + (tid >> 5) * 8;
  const int col = tid & 31;
  float acc[8];
  gemm_core(A, 64, 64, Bs, row0, col, acc);
  const float bb = bias[c0 + col];
  if (kind == 0) {
    const float SCL = 0.17677669529663687f * 1.4426950408889634f;  // 1/sqrt(32) * log2(e)
    #pragma unroll
    for (int r = 0; r < 8; ++r)
      qb[(size_t)(row0 + r) * 64 + c0 + col] = f2bf((acc[r] + bb) * SCL);
  } else if (kind == 1) {
    #pragma unroll
    for (int r = 0; r < 8; ++r)
      kb[(size_t)(row0 + r) * 64 + c0 + col] = f2bf(acc[r] + bb);
  } else {
    const int rl = (tid >> 5) * 8;
    #pragma unroll
    for (int r = 0; r < 8; ++r) Ts[col][rl + r] = acc[r] + bb;
    __syncthreads();
    const int c = tid >> 3, rr = (tid & 7) * 8;
    short8 pk;
    #pragma unroll
    for (int j = 0; j < 8; ++j) pk[j] = (short)f2bf(Ts[c][rr + j]);
    *(short8*)(Vt + (size_t)(c0 + c) * NN + blockIdx.x * 64 + rr) = pk;
  }
}

// ---------------- attention pass 1: softmax denominators (swapped mfma) ----------------
// grid (64,8), 512 thr (8 waves; 16 q-rows each). Block = 128 q-rows x 1024-key split.
// S^T = mfma(K, Q): lane (ql,quad) reg r holds S[q0+ql][kt*16+quad*4+r] -> the row
// sum for q=q0+ql is lane-local + a 2-step quad reduce (vs 4-step ql reduce before).
__global__ __launch_bounds__(512) void att_lsum_k(
    const unsigned short* __restrict__ qb, const unsigned short* __restrict__ kb,
    float* __restrict__ lsum) {
  __shared__ __align__(16) short Kbuf[2][64 * 64];
  const int tid = threadIdx.x;
  const int lane = tid & 63, wv = tid >> 6;
  const int ql = lane & 15, quad = lane >> 4;
  const int q0 = blockIdx.x * 128 + wv * 16;
  const int k0 = blockIdx.y * 1024;
  const floatx4 zf = {0.f, 0.f, 0.f, 0.f};

  short8 qf[2];
  #pragma unroll
  for (int h = 0; h < 2; ++h)
    qf[h] = *(const short8*)(qb + (size_t)(q0 + ql) * 64 + h * 32 + quad * 8);

  const int sr = tid >> 3, sc = tid & 7;     // staging: row sr (0..63), colblk sc
  const int swc = (sc ^ (sr & 7)) * 8;
  short8 krg;

  float lacc[2] = {0.f, 0.f};

  // prologue: stage tile 0
  {
    krg = *(const short8*)(kb + (size_t)(k0 + sr) * 64 + sc * 8);
    *(short8*)&Kbuf[0][sr * 64 + swc] = krg;
  }
  __syncthreads();

  for (int t = 0; t < 16; ++t) {
    if (t < 15)
      krg = *(const short8*)(kb + (size_t)(k0 + (t + 1) * 64 + sr) * 64 + sc * 8);
    const short* Kc = Kbuf[t & 1];
    #pragma unroll
    for (int kt = 0; kt < 4; ++kt) {
      const int row = kt * 16 + ql;
      short8 kf[2];
      #pragma unroll
      for (int h = 0; h < 2; ++h)
        kf[h] = *(const short8*)&Kc[row * 64 + ((h * 4 + quad) ^ (row & 7)) * 8];
      #pragma unroll
      for (int h = 0; h < 2; ++h) {
        floatx4 s = __builtin_amdgcn_mfma_f32_16x16x32_bf16(kf[h], qf[h], zf, 0, 0, 0);
        #pragma unroll
        for (int r = 0; r < 4; ++r) lacc[h] += __builtin_amdgcn_exp2f(s[r]);
      }
    }
    if (t < 15)
      *(short8*)&Kbuf[(t + 1) & 1][sr * 64 + swc] = krg;
    __syncthreads();
  }

  #pragma unroll
  for (int h = 0; h < 2; ++h) {
    lacc[h] += __shfl_xor(lacc[h], 16);
    lacc[h] += __shfl_xor(lacc[h], 32);
  }
  if (lane < 16) {
    #pragma unroll
    for (int h = 0; h < 2; ++h)
      atomicAdd(&lsum[(q0 + ql) * 2 + h], lacc[h]);
  }
}

// ---------------- attention pass 2: P/attn/PV, swapped mfma (q lane-local) ----------------
// grid (64,8), 512 thr (8 waves). Block = 128 q-rows x 1024-key split; wave = 16 q-rows.
// S^T = mfma(K,Q): lane holds P[q=ql][k=kt*16+quad*4+r] -> attn head-mean is 2 float4
// stores/lane/substep (was 8 dwords); PV fragment built via cndmask+shfl (ds_bpermute)
// instead of an LDS round-trip (Esh eliminated); O^T = mfma(Vt-frag, P-frag).
__global__ __launch_bounds__(512, 4) void att_pv_k(
    const unsigned short* __restrict__ qb, const unsigned short* __restrict__ kb,
    const unsigned short* __restrict__ Vt, const float* __restrict__ lsum,
    float* __restrict__ attn, float* __restrict__ O) {
  __shared__ __align__(16) short Kbuf[2][64 * 64];
  __shared__ __align__(16) short Vbuf[2][64 * 64];
  const int tid = threadIdx.x;
  const int lane = tid & 63, wv = tid >> 6;
  const int ql = lane & 15, quad = lane >> 4;
  const int q0 = blockIdx.x * 128 + wv * 16;
  const int k0 = blockIdx.y * 1024;
  const floatx4 zf = {0.f, 0.f, 0.f, 0.f};

  short8 qf[2];
  #pragma unroll
  for (int h = 0; h < 2; ++h)
    qf[h] = *(const short8*)(qb + (size_t)(q0 + ql) * 64 + h * 32 + quad * 8);

  float invl[2];
  #pragma unroll
  for (int h = 0; h < 2; ++h)
    invl[h] = 1.0f / lsum[(q0 + ql) * 2 + h];

  const int sr = tid >> 3, sc = tid & 7;   // staging row (0..63), colblk (0..7)
  const int swc = (sc ^ (sr & 7)) * 8;
  short8 krg, vrg;

  // PV-fragment shuffle lanes: lane (ql,quad) gathers P[ql][quad*8+j] from
  // source lanes (ql, (quad&1)*2) and (ql, (quad&1)*2+1); kt_src = quad>>1.
  const int sl_lo = ql + 16 * ((quad & 1) * 2);
  const int sl_hi = sl_lo + 16;
  const bool hi_kt = quad >= 2;

  floatx4 oacc[2][2];
  #pragma unroll
  for (int h = 0; h < 2; ++h)
    #pragma unroll
    for (int hf = 0; hf < 2; ++hf) oacc[h][hf] = zf;

  // prologue: stage tile 0
  {
    krg = *(const short8*)(kb + (size_t)(k0 + sr) * 64 + sc * 8);
    vrg = *(const short8*)(Vt + (size_t)sr * NN + k0 + sc * 8);
    *(short8*)&Kbuf[0][sr * 64 + swc] = krg;
    *(short8*)&Vbuf[0][sr * 64 + swc] = vrg;
  }
  __syncthreads();

  for (int t = 0; t < 16; ++t) {
    if (t < 15) {
      krg = *(const short8*)(kb + (size_t)(k0 + (t + 1) * 64 + sr) * 64 + sc * 8);
      vrg = *(const short8*)(Vt + (size_t)sr * NN + k0 + (t + 1) * 64 + sc * 8);
    }
    const short* Kc = Kbuf[t & 1];
    const short* Vc = Vbuf[t & 1];
    #pragma unroll
    for (int ks = 0; ks < 2; ++ks) {
      short8 kf[2][2], vf[2][2];
      #pragma unroll
      for (int kt = 0; kt < 2; ++kt) {
        const int row = ks * 32 + kt * 16 + ql;
        #pragma unroll
        for (int h = 0; h < 2; ++h)
          kf[kt][h] = *(const short8*)&Kc[row * 64 + ((h * 4 + quad) ^ (row & 7)) * 8];
      }
      #pragma unroll
      for (int h = 0; h < 2; ++h)
        #pragma unroll
        for (int hf = 0; hf < 2; ++hf) {
          const int d = h * 32 + hf * 16 + ql;
          vf[h][hf] = *(const short8*)&Vc[d * 64 + ((ks * 4 + quad) ^ (d & 7)) * 8];
        }

      floatx4 p[2][2];  // [head][kt]; reg r = P[q0+ql][ks*32 + kt*16 + quad*4 + r]
      #pragma unroll
      for (int h = 0; h < 2; ++h)
        #pragma unroll
        for (int kt = 0; kt < 2; ++kt) {
          floatx4 s = __builtin_amdgcn_mfma_f32_16x16x32_bf16(kf[kt][h], qf[h], zf, 0, 0, 0);
          #pragma unroll
          for (int r = 0; r < 4; ++r)
            p[h][kt][r] = __builtin_amdgcn_exp2f(s[r]) * invl[h];
        }
      // attn head-mean: one float4 per kt per lane (contiguous k)
      #pragma unroll
      for (int kt = 0; kt < 2; ++kt) {
        float4 m;
        m.x = 0.5f * (p[0][kt][0] + p[1][kt][0]);
        m.y = 0.5f * (p[0][kt][1] + p[1][kt][1]);
        m.z = 0.5f * (p[0][kt][2] + p[1][kt][2]);
        m.w = 0.5f * (p[0][kt][3] + p[1][kt][3]);
        *(float4*)&attn[(size_t)(q0 + ql) * NN + k0 + t * 64 + ks * 32 + kt * 16 + quad * 4] = m;
      }
      // build P B-fragment [q=ql, k=quad*8+j] via cndmask + shfl, then PV mfma
      #pragma unroll
      for (int h = 0; h < 2; ++h) {
        float t0 = hi_kt ? p[h][1][0] : p[h][0][0];
        float t1 = hi_kt ? p[h][1][1] : p[h][0][1];
        float t2 = hi_kt ? p[h][1][2] : p[h][0][2];
        float t3 = hi_kt ? p[h][1][3] : p[h][0][3];
        short8 ef;
        ef[0] = (short)f2bf(__shfl(t0, sl_lo));
        ef[1] = (short)f2bf(__shfl(t1, sl_lo));
        ef[2] = (short)f2bf(__shfl(t2, sl_lo));
        ef[3] = (short)f2bf(__shfl(t3, sl_lo));
        ef[4] = (short)f2bf(__shfl(t0, sl_hi));
        ef[5] = (short)f2bf(__shfl(t1, sl_hi));
        ef[6] = (short)f2bf(__shfl(t2, sl_hi));
        ef[7] = (short)f2bf(__shfl(t3, sl_hi));
        #pragma unroll
        for (int hf = 0; hf < 2; ++hf)
          oacc[h][hf] = __builtin_amdgcn_mfma_f32_16x16x32_bf16(vf[h][hf], ef, oacc[h][hf], 0, 0, 0);
      }
    }
    if (t < 15) {
      *(short8*)&Kbuf[(t + 1) & 1][sr * 64 + swc] = krg;
      *(short8*)&Vbuf[(t + 1) & 1][sr * 64 + swc] = vrg;
    }
    __syncthreads();
  }

  // O^T layout: lane (ql,quad) reg r = O[q0+ql][h*32 + hf*16 + quad*4 + r]
  #pragma unroll
  for (int h = 0; h < 2; ++h)
    #pragma unroll
    for (int hf = 0; hf < 2; ++hf)
      #pragma unroll
      for (int r = 0; r < 4; ++r)
        atomicAdd(&O[(size_t)(q0 + ql) * 64 + h * 32 + hf * 16 + quad * 4 + r], oacc[h][hf][r]);
}

// ---------------- tail: h_attn=O@Wo+bo ; y1=relu([htkg|h_attn]@fc1+b) ; pred=y1@fc2+b ----
__global__ __launch_bounds__(256) void tail_k(const float* __restrict__ O,
    const float* __restrict__ htkg, const float* __restrict__ Wo, const float* __restrict__ bo,
    const float* __restrict__ fc1W, const float* __restrict__ fc1b,
    const float* __restrict__ fc2W, const float* __restrict__ fc2b,
    float* __restrict__ pred) {
  __shared__ float Ws[8192];
  __shared__ float T1[2048];
  __shared__ float T2[2048];
  const int tid = threadIdx.x;
  const int col = tid & 63, rg = tid >> 6;
  const int rowbase = blockIdx.x * 32;
  for (int i = tid; i < 2048; i += 256) T1[i] = O[(size_t)rowbase * 64 + i];
  for (int i = tid; i < 4096; i += 256) Ws[i] = Wo[i];
  const float rbo = bo[col], rf1b = fc1b[col], rf2 = fc2W[col], rf2b = fc2b[0];
  __syncthreads();
  float ha[8];
  #pragma unroll
  for (int r = 0; r < 8; ++r) {
    const int row = rg * 8 + r;
    float acc = rbo;
    for (int k = 0; k < 64; ++k) acc = fmaf(T1[row * 64 + k], Ws[k * 64 + col], acc);
    ha[r] = acc;
  }
  __syncthreads();
  #pragma unroll
  for (int r = 0; r < 8; ++r) T2[(rg * 8 + r) * 64 + col] = ha[r];
  for (int i = tid; i < 2048; i += 256) T1[i] = htkg[(size_t)rowbase * 64 + i];
  for (int i = tid; i < 8192; i += 256) Ws[i] = fc1W[i];
  __syncthreads();
  #pragma unroll
  for (int r = 0; r < 8; ++r) {
    const int row = rg * 8 + r;
    float acc = rf1b;
    for (int k = 0; k < 64; ++k) acc = fmaf(T1[row * 64 + k], Ws[k * 64 + col], acc);
    for (int k = 0; k < 64; ++k) acc = fmaf(T2[row * 64 + k], Ws[(64 + k) * 64 + col], acc);
    float y = fmaxf(acc, 0.f);
    float v = y * rf2;
    #pragma unroll
    for (int m = 32; m >= 1; m >>= 1) v += __shfl_xor(v, m);
    if (col == 0) pred[rowbase + row] = v + rf2b;
  }
}

extern "C" void kernel_launch(void* const* d_in, const int* in_sizes, int n_in,
                              void* d_out, int out_size, void* d_ws, size_t ws_size,
                              hipStream_t stream) {
  (void)in_sizes; (void)n_in; (void)out_size; (void)ws_size;
  const float* x       = (const float*)d_in[0];
  const int*   ei_t    = (const int*)d_in[1];
  const int*   ei_e    = (const int*)d_in[2];
  const float* gat1_W  = (const float*)d_in[3];
  const float* gat1_as = (const float*)d_in[4];
  const float* gat1_ad = (const float*)d_in[5];
  const float* gat1_b  = (const float*)d_in[6];
  const float* gat2_W  = (const float*)d_in[7];
  const float* gat2_as = (const float*)d_in[8];
  const float* gat2_ad = (const float*)d_in[9];
  const float* gat2_b  = (const float*)d_in[10];
  const float* gcn1_W  = (const float*)d_in[11];
  const float* gcn1_b  = (const float*)d_in[12];
  const float* gcn2_W  = (const float*)d_in[13];
  const float* gcn2_b  = (const float*)d_in[14];
  const float* Wq = (const float*)d_in[15]; const float* bq = (const float*)d_in[16];
  const float* Wk = (const float*)d_in[17]; const float* bk = (const float*)d_in[18];
  const float* Wv = (const float*)d_in[19]; const float* bv = (const float*)d_in[20];
  const float* Wo = (const float*)d_in[21]; const float* bo = (const float*)d_in[22];
  const float* fc1_W = (const float*)d_in[23]; const float* fc1_b = (const float*)d_in[24];
  const float* fc2_W = (const float*)d_in[25]; const float* fc2_b = (const float*)d_in[26];

  float* out  = (float*)d_out;
  float* attn = out + NN;   // [N, N] fp32, after pred[N]

  char* wsp = (char*)d_ws;
  size_t ofs = 0;
  auto take = [&](size_t bytes) -> char* {
    char* p = wsp + ofs;
    ofs = (ofs + bytes + 255) & ~(size_t)255;
    return p;
  };
  // ---- contiguous zero-init region first (single memset) ----
  int*   pos_t = (int*)take(NN * 4);
  int*   pos_e = (int*)take(NN * 4);
  float* a_s1  = (float*)take((size_t)NN * 2 * 4);
  float* a_d1  = (float*)take((size_t)NN * 2 * 4);
  float* a_s2  = (float*)take((size_t)NN * 4);
  float* a_d2  = (float*)take((size_t)NN * 4);
  float* a_l   = (float*)take((size_t)NN * 2 * 4);
  float* Obuf  = (float*)take((size_t)NN * 64 * 4);
  const size_t zero_span = ofs;
  // ---- rest ----
  int* off_t = (int*)take((NN + 1) * 4);
  int* off_e = (int*)take((NN + 1) * 4);
  int* src_t = (int*)take((size_t)ET * 4);
  int* src_e = (int*)take((size_t)ET * 4);
  float* h1    = (float*)take((size_t)NN * 128 * 4);
  float* g1out = (float*)take((size_t)NN * 128 * 4);
  float* h2    = (float*)take((size_t)NN * 64 * 4);
  float* htkg  = (float*)take((size_t)NN * 64 * 4);
  float* hg1   = (float*)take((size_t)NN * 64 * 4);
  float* h2g   = (float*)take((size_t)NN * 64 * 4);
  float* hekg  = (float*)take((size_t)NN * 64 * 4);
  unsigned short* qb = (unsigned short*)take((size_t)NN * 64 * 2);
  unsigned short* kb = (unsigned short*)take((size_t)NN * 64 * 2);
  unsigned short* Vt = (unsigned short*)take((size_t)64 * NN * 2);

  hipMemsetAsync(wsp, 0, zero_span, stream);

  // CSR for both graphs
  edge_hist2_k<<<2 * ET / 256, 256, 0, stream>>>(ei_t, ei_e, pos_t, pos_e);
  scan2_k<<<2, 1024, 0, stream>>>(pos_t, off_t, pos_e, off_e);
  edge_scatter2_k<<<2 * ET / 256, 256, 0, stream>>>(ei_t, ei_e, pos_t, pos_e, src_t, src_e);

  // x projections for both branches + gat1 att_sd epilogue
  mm_x_k<<<dim3(128, 6), 256, 0, stream>>>(x, gat1_W, gcn1_W, gat1_as, gat1_ad,
                                           h1, hg1, a_s1, a_d1);
  // merged gat1-agg + gcn1-agg+gemv
  agg1_k<<<NN + NN / 2, 128, 0, stream>>>(h1, a_s1, a_d1, off_t, src_t, gat1_b, g1out,
                                          hg1, off_e, src_e, gcn1_b, gcn2_W, h2g);
  // merged mm_gat2 + gcn_agg2
  mm2_k<<<256 + NN / 4, 256, 0, stream>>>(g1out, gat2_W, gat2_as, gat2_ad, h2, a_s2, a_d2,
                                          h2g, off_e, src_e, gcn2_b, hekg);
  // gat layer-2 aggregation
  gat_agg_k<1, 64><<<NN, 64, 0, stream>>>(h2, a_s2, a_d2, off_t, src_t, gat2_b, htkg, 64);

  // qkv projections + V transpose
  mm_qkv_k<<<dim3(128, 6), 256, 0, stream>>>(htkg, hekg, Wq, bq, Wk, bk, Wv, bv, qb, kb, Vt);

  // attention: q-block 128 x k-split 8, LDS-shared K/V tiles, swapped-operand mfma
  att_lsum_k<<<dim3(64, 8), 512, 0, stream>>>(qb, kb, a_l);
  att_pv_k<<<dim3(64, 8), 512, 0, stream>>>(qb, kb, Vt, a_l, attn, Obuf);

  // fused epilogue: Wo + fc1 + fc2
  tail_k<<<256, 256, 0, stream>>>(Obuf, htkg, Wo, bo, fc1_W, fc1_b, fc2_W, fc2_b, out);
}

// Round 8
// 601.624 us; speedup vs baseline: 1.0118x; 1.0118x over previous
//
#include <hip/hip_runtime.h>
#include <cstdint>
#include <cstddef>

#define NN 8192
#define EE 262144
#define ET 270336   // EE + NN self loops

using short8  = __attribute__((ext_vector_type(8))) short;
using floatx4 = __attribute__((ext_vector_type(4))) float;

__device__ __forceinline__ unsigned short f2bf(float f) {
  unsigned int u = __float_as_uint(f);
  u += 0x7fffu + ((u >> 16) & 1u);          // RNE
  return (unsigned short)(u >> 16);
}

// ---------------- CSR build, both graphs in one launch ----------------
__global__ void edge_hist2_k(const int* __restrict__ ei_t, const int* __restrict__ ei_e,
                             int* __restrict__ cnt_t, int* __restrict__ cnt_e) {
  int idx = blockIdx.x * 256 + threadIdx.x;
  int g = idx >= ET;                        // block-uniform (ET % 256 == 0)
  int e = g ? idx - ET : idx;
  const int* ei = g ? ei_e : ei_t;
  int* cnt = g ? cnt_e : cnt_t;
  int d = (e < EE) ? ei[EE + e] : (e - EE);
  atomicAdd(&cnt[d], 1);
}

__global__ void scan2_k(int* cnt_t, int* off_t, int* cnt_e, int* off_e) {
  int* cnt = blockIdx.x ? cnt_e : cnt_t;    // pos aliases cnt (overwritten)
  int* off = blockIdx.x ? off_e : off_t;
  __shared__ int s[1024];
  int t = threadIdx.x;
  int v[8]; int base = t * 8; int sum = 0;
  #pragma unroll
  for (int j = 0; j < 8; ++j) { v[j] = cnt[base + j]; sum += v[j]; }
  s[t] = sum; __syncthreads();
  for (int o = 1; o < 1024; o <<= 1) {
    int x = (t >= o) ? s[t - o] : 0;
    __syncthreads();
    s[t] += x;
    __syncthreads();
  }
  int excl = s[t] - sum;
  #pragma unroll
  for (int j = 0; j < 8; ++j) { off[base + j] = excl; cnt[base + j] = excl; excl += v[j]; }
  if (t == 1023) off[NN] = excl;
}

__global__ void edge_scatter2_k(const int* __restrict__ ei_t, const int* __restrict__ ei_e,
                                int* __restrict__ pos_t, int* __restrict__ pos_e,
                                int* __restrict__ srcs_t, int* __restrict__ srcs_e) {
  int idx = blockIdx.x * 256 + threadIdx.x;
  int g = idx >= ET;
  int e = g ? idx - ET : idx;
  const int* ei = g ? ei_e : ei_t;
  int* pos = g ? pos_e : pos_t;
  int* srcs = g ? srcs_e : srcs_t;
  int sv, d;
  if (e < EE) { sv = ei[e]; d = ei[EE + e]; } else { sv = d = e - EE; }
  int p = atomicAdd(&pos[d], 1);
  srcs[p] = sv;
}

// ---------------- shared GEMM inner loop ----------------
__device__ __forceinline__ void gemm_core(const float* __restrict__ A, int lda, int K,
                                          const float* __restrict__ Bs, int row0, int col,
                                          float acc[8]) {
  #pragma unroll
  for (int r = 0; r < 8; ++r) acc[r] = 0.f;
  for (int k = 0; k < K; k += 4) {
    float b0 = Bs[(k + 0) * 32 + col], b1 = Bs[(k + 1) * 32 + col];
    float b2 = Bs[(k + 2) * 32 + col], b3 = Bs[(k + 3) * 32 + col];
    #pragma unroll
    for (int r = 0; r < 8; ++r) {
      const float4 a4 = *(const float4*)(A + (size_t)(row0 + r) * lda + k);
      acc[r] = fmaf(a4.x, b0, acc[r]);
      acc[r] = fmaf(a4.y, b1, acc[r]);
      acc[r] = fmaf(a4.z, b2, acc[r]);
      acc[r] = fmaf(a4.w, b3, acc[r]);
    }
  }
}

// ---------------- mm_x: h1 = x@gat1_W (+att_sd epilogue), hg1 = x@gcn1_W ----------------
__global__ __launch_bounds__(256) void mm_x_k(const float* __restrict__ x,
    const float* __restrict__ Wgat, const float* __restrict__ Wgcn,
    const float* __restrict__ as_w, const float* __restrict__ ad_w,
    float* __restrict__ h1, float* __restrict__ hg1,
    float* __restrict__ a_s1, float* __restrict__ a_d1) {
  __shared__ float Bs[256 * 32];
  const int tid = threadIdx.x, by = blockIdx.y;
  const bool gat = by < 4;
  const int NC = gat ? 128 : 64;
  const int c0 = gat ? by * 32 : (by - 4) * 32;
  const float* B = gat ? Wgat : Wgcn;
  for (int idx = tid; idx < 256 * 32; idx += 256)
    Bs[idx] = B[(idx >> 5) * NC + c0 + (idx & 31)];
  __syncthreads();
  const int row0 = blockIdx.x * 64 + (tid >> 5) * 8;
  const int col = tid & 31;
  float acc[8];
  gemm_core(x, 256, 256, Bs, row0, col, acc);
  if (gat) {
    #pragma unroll
    for (int r = 0; r < 8; ++r) h1[(size_t)(row0 + r) * 128 + c0 + col] = acc[r];
    const int head = c0 >> 6;
    const float asw = as_w[head * 64 + (c0 & 63) + col];
    const float adw = ad_w[head * 64 + (c0 & 63) + col];
    float ps[8], pd[8];
    #pragma unroll
    for (int r = 0; r < 8; ++r) { ps[r] = acc[r] * asw; pd[r] = acc[r] * adw; }
    #pragma unroll
    for (int m = 16; m >= 1; m >>= 1)
      #pragma unroll
      for (int r = 0; r < 8; ++r) { ps[r] += __shfl_xor(ps[r], m); pd[r] += __shfl_xor(pd[r], m); }
    if (col == 0) {
      #pragma unroll
      for (int r = 0; r < 8; ++r) {
        atomicAdd(&a_s1[(row0 + r) * 2 + head], ps[r]);
        atomicAdd(&a_d1[(row0 + r) * 2 + head], pd[r]);
      }
    }
  } else {
    #pragma unroll
    for (int r = 0; r < 8; ++r) hg1[(size_t)(row0 + r) * 64 + c0 + col] = acc[r];
  }
}

// ---------------- GAT aggregation ----------------
template<int H, int C>
__device__ __forceinline__ void gat_agg_body(const float* __restrict__ h,
    const float* __restrict__ a_s, const float* __restrict__ a_d,
    const int* __restrict__ off, const int* __restrict__ srcs,
    const float* __restrict__ bias, float* __restrict__ out, int ldout, int b) {
  constexpr int HC = H * C;
  const int tid = threadIdx.x;
  const int hd = tid / C;
  const int r0 = off[b], r1 = off[b + 1];
  __shared__ int s_src[HC];
  __shared__ float s_w[HC][H];
  float ad[H];
  #pragma unroll
  for (int hh = 0; hh < H; ++hh) ad[hh] = a_d[b * H + hh];
  float acc = 0.f, den = 0.f;
  for (int base = r0; base < r1; base += HC) {
    const int cnt = min(HC, r1 - base);
    const int cnt4 = (cnt + 3) & ~3;
    __syncthreads();
    int e = base + tid;
    if (e < r1) {
      int sv = srcs[e];
      s_src[tid] = sv;
      #pragma unroll
      for (int hh = 0; hh < H; ++hh) {
        float xv = a_s[sv * H + hh] + ad[hh];
        xv = xv > 0.f ? xv : 0.2f * xv;     // leaky_relu 0.2
        s_w[tid][hh] = __expf(xv);
      }
    } else if (tid < cnt4) {                // zero-weight padding
      s_src[tid] = 0;
      #pragma unroll
      for (int hh = 0; hh < H; ++hh) s_w[tid][hh] = 0.f;
    }
    __syncthreads();
    for (int j = 0; j < cnt4; j += 4) {
      #pragma unroll
      for (int u = 0; u < 4; ++u) {
        float wv = s_w[j + u][hd];
        den += wv;
        acc = fmaf(wv, h[(size_t)s_src[j + u] * HC + tid], acc);
      }
    }
  }
  float o = acc / den + bias[tid];
  out[(size_t)b * ldout + tid] = o > 0.f ? o : (__expf(o) - 1.f);  // elu
}

template<int H, int C>
__global__ void gat_agg_k(const float* __restrict__ h, const float* __restrict__ a_s,
                          const float* __restrict__ a_d, const int* __restrict__ off,
                          const int* __restrict__ srcs, const float* __restrict__ bias,
                          float* __restrict__ out, int ldout) {
  gat_agg_body<H, C>(h, a_s, a_d, off, srcs, bias, out, ldout, blockIdx.x);
}

// ---------------- merged: gat1 aggregation (blocks 0..NN) + gcn1 agg+gemv (2 nodes/blk) ----
__global__ __launch_bounds__(128) void agg1_k(
    const float* __restrict__ h1, const float* __restrict__ a_s1, const float* __restrict__ a_d1,
    const int* __restrict__ off_t, const int* __restrict__ src_t,
    const float* __restrict__ gat1_b, float* __restrict__ g1out,
    const float* __restrict__ hg1, const int* __restrict__ off_e, const int* __restrict__ src_e,
    const float* __restrict__ gcn1_b, const float* __restrict__ gcn2_W, float* __restrict__ h2g) {
  const int tid = threadIdx.x;
  if (blockIdx.x < NN) {
    gat_agg_body<2, 64>(h1, a_s1, a_d1, off_t, src_t, gat1_b, g1out, 128, blockIdx.x);
  } else {
    const int nb = (blockIdx.x - NN) * 2;
    const int sub = tid >> 6, t = tid & 63;
    const int node = nb + sub;
    __shared__ int s_src2[2][64];
    __shared__ float s_nrm2[2][64];
    __shared__ float s_row2[2][64];
    const int r0 = off_e[node], r1 = off_e[node + 1];
    const int cA = off_e[nb + 1] - off_e[nb];
    const int cB = off_e[nb + 2] - off_e[nb + 1];
    const int trips = (max(cA, cB) + 63) >> 6;
    float dinv_b = rsqrtf((float)max(r1 - r0, 1));
    float acc = 0.f;
    for (int it = 0; it < trips; ++it) {
      const int cnt = min(64, r1 - (r0 + it * 64));
      const int cnt4 = (cnt + 3) & ~3;
      __syncthreads();
      int e = r0 + it * 64 + t;
      if (e < r1) {
        int sv = src_e[e];
        s_src2[sub][t] = sv;
        int ds = off_e[sv + 1] - off_e[sv];
        s_nrm2[sub][t] = dinv_b * rsqrtf((float)max(ds, 1));
      } else if (t < cnt4) {
        s_src2[sub][t] = 0;
        s_nrm2[sub][t] = 0.f;
      }
      __syncthreads();
      for (int j = 0; j < cnt4; j += 4) {
        #pragma unroll
        for (int u = 0; u < 4; ++u)
          acc = fmaf(s_nrm2[sub][j + u], hg1[(size_t)s_src2[sub][j + u] * 64 + t], acc);
      }
    }
    s_row2[sub][t] = fmaxf(acc + gcn1_b[t], 0.f);
    __syncthreads();
    float acc2 = 0.f;
    for (int k = 0; k < 64; ++k)
      acc2 = fmaf(s_row2[sub][k], gcn2_W[k * 64 + t], acc2);
    h2g[(size_t)node * 64 + t] = acc2;
  }
}

// ---------------- merged: mm_gat2 (blocks 0..256) + gcn_agg2 (4 nodes/blk) ----------------
__global__ __launch_bounds__(256) void mm2_k(
    const float* __restrict__ g1out, const float* __restrict__ gat2_W,
    const float* __restrict__ gat2_as, const float* __restrict__ gat2_ad,
    float* __restrict__ h2, float* __restrict__ a_s2, float* __restrict__ a_d2,
    const float* __restrict__ h2g, const int* __restrict__ off_e, const int* __restrict__ src_e,
    const float* __restrict__ gcn2_b, float* __restrict__ hekg) {
  const int tid = threadIdx.x;
  if (blockIdx.x < 256) {
    __shared__ float Bs[128 * 32];
    const int bx = blockIdx.x & 127;
    const int c0 = (blockIdx.x >> 7) * 32;
    for (int idx = tid; idx < 128 * 32; idx += 256)
      Bs[idx] = gat2_W[(idx >> 5) * 64 + c0 + (idx & 31)];
    __syncthreads();
    const int row0 = bx * 64 + (tid >> 5) * 8;
    const int col = tid & 31;
    float acc[8];
    gemm_core(g1out, 128, 128, Bs, row0, col, acc);
    const float asw = gat2_as[c0 + col];
    const float adw = gat2_ad[c0 + col];
    float ps[8], pd[8];
    #pragma unroll
    for (int r = 0; r < 8; ++r) {
      h2[(size_t)(row0 + r) * 64 + c0 + col] = acc[r];
      ps[r] = acc[r] * asw; pd[r] = acc[r] * adw;
    }
    #pragma unroll
    for (int m = 16; m >= 1; m >>= 1)
      #pragma unroll
      for (int r = 0; r < 8; ++r) { ps[r] += __shfl_xor(ps[r], m); pd[r] += __shfl_xor(pd[r], m); }
    if (col == 0) {
      #pragma unroll
      for (int r = 0; r < 8; ++r) {
        atomicAdd(&a_s2[row0 + r], ps[r]);
        atomicAdd(&a_d2[row0 + r], pd[r]);
      }
    }
  } else {
    const int nb = (blockIdx.x - 256) * 4;
    const int sub = tid >> 6, t = tid & 63;
    const int node = nb + sub;
    __shared__ int s_src4[4][64];
    __shared__ float s_nrm4[4][64];
    const int r0 = off_e[node], r1 = off_e[node + 1];
    int cmax = 0;
    #pragma unroll
    for (int i = 0; i < 4; ++i) cmax = max(cmax, off_e[nb + i + 1] - off_e[nb + i]);
    const int trips = (cmax + 63) >> 6;
    float dinv_b = rsqrtf((float)max(r1 - r0, 1));
    float acc = 0.f;
    for (int it = 0; it < trips; ++it) {
      const int cnt = min(64, r1 - (r0 + it * 64));
      const int cnt4 = (cnt + 3) & ~3;
      __syncthreads();
      int e = r0 + it * 64 + t;
      if (e < r1) {
        int sv = src_e[e];
        s_src4[sub][t] = sv;
        int ds = off_e[sv + 1] - off_e[sv];
        s_nrm4[sub][t] = dinv_b * rsqrtf((float)max(ds, 1));
      } else if (t < cnt4) {
        s_src4[sub][t] = 0;
        s_nrm4[sub][t] = 0.f;
      }
      __syncthreads();
      for (int j = 0; j < cnt4; j += 4) {
        #pragma unroll
        for (int u = 0; u < 4; ++u)
          acc = fmaf(s_nrm4[sub][j + u], h2g[(size_t)s_src4[sub][j + u] * 64 + t], acc);
      }
    }
    hekg[(size_t)node * 64 + t] = fmaxf(acc + gcn2_b[t], 0.f);
  }
}

// ---------------- qkv projections (+V transpose) ----------------
__global__ __launch_bounds__(256) void mm_qkv_k(const float* __restrict__ htkg,
    const float* __restrict__ hekg,
    const float* __restrict__ Wq, const float* __restrict__ bq,
    const float* __restrict__ Wk, const float* __restrict__ bk,
    const float* __restrict__ Wv, const float* __restrict__ bv,
    unsigned short* __restrict__ qb, unsigned short* __restrict__ kb,
    unsigned short* __restrict__ Vt) {
  __shared__ float Bs[64 * 32];
  __shared__ float Ts[32][65];
  const int tid = threadIdx.x, by = blockIdx.y;
  const int kind = by >> 1;
  const int c0 = (by & 1) * 32;
  const float* A = (kind == 0) ? htkg : hekg;
  const float* B = (kind == 0) ? Wq : (kind == 1) ? Wk : Wv;
  const float* bias = (kind == 0) ? bq : (kind == 1) ? bk : bv;
  for (int idx = tid; idx < 64 * 32; idx += 256)
    Bs[idx] = B[(idx >> 5) * 64 + c0 + (idx & 31)];
  __syncthreads();
  const int row0 = blockIdx.x * 64 + (tid >> 5) * 8;
  const int col = tid & 31;
  float acc[8];
  gemm_core(A, 64, 64, Bs, row0, col, acc);
  const float bb = bias[c0 + col];
  if (kind == 0) {
    const float SCL = 0.17677669529663687f * 1.4426950408889634f;  // 1/sqrt(32) * log2(e)
    #pragma unroll
    for (int r = 0; r < 8; ++r)
      qb[(size_t)(row0 + r) * 64 + c0 + col] = f2bf((acc[r] + bb) * SCL);
  } else if (kind == 1) {
    #pragma unroll
    for (int r = 0; r < 8; ++r)
      kb[(size_t)(row0 + r) * 64 + c0 + col] = f2bf(acc[r] + bb);
  } else {
    const int rl = (tid >> 5) * 8;
    #pragma unroll
    for (int r = 0; r < 8; ++r) Ts[col][rl + r] = acc[r] + bb;
    __syncthreads();
    const int c = tid >> 3, rr = (tid & 7) * 8;
    short8 pk;
    #pragma unroll
    for (int j = 0; j < 8; ++j) pk[j] = (short)f2bf(Ts[c][rr + j]);
    *(short8*)(Vt + (size_t)(c0 + c) * NN + blockIdx.x * 64 + rr) = pk;
  }
}

// ---------------- attention pass 1: softmax denominators (swapped mfma) ----------------
// grid (64,8), 512 thr (8 waves; 16 q-rows each). Block = 128 q-rows x 1024-key split.
// S^T = mfma(K, Q): lane (ql,quad) reg r holds S[q0+ql][kt*16+quad*4+r] -> row sum for
// q=q0+ql is lane-local + 2-step quad reduce. (Verified correct in round 6.)
__global__ __launch_bounds__(512) void att_lsum_k(
    const unsigned short* __restrict__ qb, const unsigned short* __restrict__ kb,
    float* __restrict__ lsum) {
  __shared__ __align__(16) short Kbuf[2][64 * 64];
  const int tid = threadIdx.x;
  const int lane = tid & 63, wv = tid >> 6;
  const int ql = lane & 15, quad = lane >> 4;
  const int q0 = blockIdx.x * 128 + wv * 16;
  const int k0 = blockIdx.y * 1024;
  const floatx4 zf = {0.f, 0.f, 0.f, 0.f};

  short8 qf[2];
  #pragma unroll
  for (int h = 0; h < 2; ++h)
    qf[h] = *(const short8*)(qb + (size_t)(q0 + ql) * 64 + h * 32 + quad * 8);

  const int sr = tid >> 3, sc = tid & 7;     // staging: row sr (0..63), colblk sc
  const int swc = (sc ^ (sr & 7)) * 8;
  short8 krg;

  float lacc[2] = {0.f, 0.f};

  // prologue: stage tile 0
  {
    krg = *(const short8*)(kb + (size_t)(k0 + sr) * 64 + sc * 8);
    *(short8*)&Kbuf[0][sr * 64 + swc] = krg;
  }
  __syncthreads();

  for (int t = 0; t < 16; ++t) {
    if (t < 15)
      krg = *(const short8*)(kb + (size_t)(k0 + (t + 1) * 64 + sr) * 64 + sc * 8);
    const short* Kc = Kbuf[t & 1];
    #pragma unroll
    for (int kt = 0; kt < 4; ++kt) {
      const int row = kt * 16 + ql;
      short8 kf[2];
      #pragma unroll
      for (int h = 0; h < 2; ++h)
        kf[h] = *(const short8*)&Kc[row * 64 + ((h * 4 + quad) ^ (row & 7)) * 8];
      #pragma unroll
      for (int h = 0; h < 2; ++h) {
        floatx4 s = __builtin_amdgcn_mfma_f32_16x16x32_bf16(kf[h], qf[h], zf, 0, 0, 0);
        #pragma unroll
        for (int r = 0; r < 4; ++r) lacc[h] += __builtin_amdgcn_exp2f(s[r]);
      }
    }
    if (t < 15)
      *(short8*)&Kbuf[(t + 1) & 1][sr * 64 + swc] = krg;
    __syncthreads();
  }

  #pragma unroll
  for (int h = 0; h < 2; ++h) {
    lacc[h] += __shfl_xor(lacc[h], 16);
    lacc[h] += __shfl_xor(lacc[h], 32);
  }
  if (lane < 16) {
    #pragma unroll
    for (int h = 0; h < 2; ++h)
      atomicAdd(&lsum[(q0 + ql) * 2 + h], lacc[h]);
  }
}

// ---------------- attention pass 2: P/attn/PV, swapped mfma + vectorized Esh ----------------
// grid (64,8), 512 thr (8 waves). Block = 128 q-rows x 1024-key split; wave = 16 q-rows.
// S^T = mfma(K,Q): lane holds P[q=ql][k=kt*16+quad*4+r] contiguous in k -> attn head-mean
// is float4 stores, and the Esh staging is 2 ds_write_b128 + 2 ds_read_b128 per head
// (r5: 16 ds_write_b32 + 2 b128; r6's 16 ds_bpermute chain regressed).
// O^T = mfma(Vt-frag, P-frag); O partials via global f32 atomics into zeroed Obuf.
__global__ __launch_bounds__(512, 4) void att_pv_k(
    const unsigned short* __restrict__ qb, const unsigned short* __restrict__ kb,
    const unsigned short* __restrict__ Vt, const float* __restrict__ lsum,
    float* __restrict__ attn, float* __restrict__ O) {
  __shared__ __align__(16) short Kbuf[2][64 * 64];
  __shared__ __align__(16) short Vbuf[2][64 * 64];
  __shared__ __align__(16) float Esh[8][2][16 * 36];  // [wave][head][16q x 32k pad36]
  const int tid = threadIdx.x;
  const int lane = tid & 63, wv = tid >> 6;
  const int ql = lane & 15, quad = lane >> 4;
  const int q0 = blockIdx.x * 128 + wv * 16;
  const int k0 = blockIdx.y * 1024;
  const floatx4 zf = {0.f, 0.f, 0.f, 0.f};

  short8 qf[2];
  #pragma unroll
  for (int h = 0; h < 2; ++h)
    qf[h] = *(const short8*)(qb + (size_t)(q0 + ql) * 64 + h * 32 + quad * 8);

  float invl[2];
  #pragma unroll
  for (int h = 0; h < 2; ++h)
    invl[h] = 1.0f / lsum[(q0 + ql) * 2 + h];

  const int sr = tid >> 3, sc = tid & 7;   // staging row (0..63), colblk (0..7)
  const int swc = (sc ^ (sr & 7)) * 8;
  short8 krg, vrg;

  floatx4 oacc[2][2];
  #pragma unroll
  for (int h = 0; h < 2; ++h)
    #pragma unroll
    for (int hf = 0; hf < 2; ++hf) oacc[h][hf] = zf;

  // prologue: stage tile 0
  {
    krg = *(const short8*)(kb + (size_t)(k0 + sr) * 64 + sc * 8);
    vrg = *(const short8*)(Vt + (size_t)sr * NN + k0 + sc * 8);
    *(short8*)&Kbuf[0][sr * 64 + swc] = krg;
    *(short8*)&Vbuf[0][sr * 64 + swc] = vrg;
  }
  __syncthreads();

  for (int t = 0; t < 16; ++t) {
    if (t < 15) {
      krg = *(const short8*)(kb + (size_t)(k0 + (t + 1) * 64 + sr) * 64 + sc * 8);
      vrg = *(const short8*)(Vt + (size_t)sr * NN + k0 + (t + 1) * 64 + sc * 8);
    }
    const short* Kc = Kbuf[t & 1];
    const short* Vc = Vbuf[t & 1];
    #pragma unroll
    for (int ks = 0; ks < 2; ++ks) {
      short8 kf[2][2], vf[2][2];
      #pragma unroll
      for (int kt = 0; kt < 2; ++kt) {
        const int row = ks * 32 + kt * 16 + ql;
        #pragma unroll
        for (int h = 0; h < 2; ++h)
          kf[kt][h] = *(const short8*)&Kc[row * 64 + ((h * 4 + quad) ^ (row & 7)) * 8];
      }
      #pragma unroll
      for (int h = 0; h < 2; ++h)
        #pragma unroll
        for (int hf = 0; hf < 2; ++hf) {
          const int d = h * 32 + hf * 16 + ql;
          vf[h][hf] = *(const short8*)&Vc[d * 64 + ((ks * 4 + quad) ^ (d & 7)) * 8];
        }

      floatx4 p[2][2];  // [head][kt]; reg r = P[q0+ql][ks*32 + kt*16 + quad*4 + r]
      #pragma unroll
      for (int h = 0; h < 2; ++h)
        #pragma unroll
        for (int kt = 0; kt < 2; ++kt) {
          floatx4 s = __builtin_amdgcn_mfma_f32_16x16x32_bf16(kf[kt][h], qf[h], zf, 0, 0, 0);
          #pragma unroll
          for (int r = 0; r < 4; ++r)
            p[h][kt][r] = __builtin_amdgcn_exp2f(s[r]) * invl[h];
        }
      // attn head-mean: one float4 per kt per lane (contiguous k)
      #pragma unroll
      for (int kt = 0; kt < 2; ++kt) {
        float4 m;
        m.x = 0.5f * (p[0][kt][0] + p[1][kt][0]);
        m.y = 0.5f * (p[0][kt][1] + p[1][kt][1]);
        m.z = 0.5f * (p[0][kt][2] + p[1][kt][2]);
        m.w = 0.5f * (p[0][kt][3] + p[1][kt][3]);
        *(float4*)&attn[(size_t)(q0 + ql) * NN + k0 + t * 64 + ks * 32 + kt * 16 + quad * 4] = m;
      }
      // q-local P -> Esh (float4 writes), b128 reads give the PV B-fragment
      #pragma unroll
      for (int h = 0; h < 2; ++h)
        #pragma unroll
        for (int kt = 0; kt < 2; ++kt)
          *(floatx4*)&Esh[wv][h][ql * 36 + kt * 16 + quad * 4] = p[h][kt];
      #pragma unroll
      for (int h = 0; h < 2; ++h) {
        const float* ep = &Esh[wv][h][ql * 36 + quad * 8];
        float4 x0 = *(const float4*)ep;      // P[ql][quad*8 .. +3]
        float4 x1 = *(const float4*)(ep + 4); // P[ql][quad*8+4 .. +7]
        short8 ef;
        ef[0] = (short)f2bf(x0.x); ef[1] = (short)f2bf(x0.y);
        ef[2] = (short)f2bf(x0.z); ef[3] = (short)f2bf(x0.w);
        ef[4] = (short)f2bf(x1.x); ef[5] = (short)f2bf(x1.y);
        ef[6] = (short)f2bf(x1.z); ef[7] = (short)f2bf(x1.w);
        #pragma unroll
        for (int hf = 0; hf < 2; ++hf)
          oacc[h][hf] = __builtin_amdgcn_mfma_f32_16x16x32_bf16(vf[h][hf], ef, oacc[h][hf], 0, 0, 0);
      }
    }
    if (t < 15) {
      *(short8*)&Kbuf[(t + 1) & 1][sr * 64 + swc] = krg;
      *(short8*)&Vbuf[(t + 1) & 1][sr * 64 + swc] = vrg;
    }
    __syncthreads();
  }

  // O^T layout: lane (ql,quad) reg r = O[q0+ql][h*32 + hf*16 + quad*4 + r]
  #pragma unroll
  for (int h = 0; h < 2; ++h)
    #pragma unroll
    for (int hf = 0; hf < 2; ++hf)
      #pragma unroll
      for (int r = 0; r < 4; ++r)
        atomicAdd(&O[(size_t)(q0 + ql) * 64 + h * 32 + hf * 16 + quad * 4 + r], oacc[h][hf][r]);
}

// ---------------- tail: h_attn=O@Wo+bo ; y1=relu([htkg|h_attn]@fc1+b) ; pred=y1@fc2+b ----
__global__ __launch_bounds__(256) void tail_k(const float* __restrict__ O,
    const float* __restrict__ htkg, const float* __restrict__ Wo, const float* __restrict__ bo,
    const float* __restrict__ fc1W, const float* __restrict__ fc1b,
    const float* __restrict__ fc2W, const float* __restrict__ fc2b,
    float* __restrict__ pred) {
  __shared__ float Ws[8192];
  __shared__ float T1[2048];
  __shared__ float T2[2048];
  const int tid = threadIdx.x;
  const int col = tid & 63, rg = tid >> 6;
  const int rowbase = blockIdx.x * 32;
  for (int i = tid; i < 2048; i += 256) T1[i] = O[(size_t)rowbase * 64 + i];
  for (int i = tid; i < 4096; i += 256) Ws[i] = Wo[i];
  const float rbo = bo[col], rf1b = fc1b[col], rf2 = fc2W[col], rf2b = fc2b[0];
  __syncthreads();
  float ha[8];
  #pragma unroll
  for (int r = 0; r < 8; ++r) {
    const int row = rg * 8 + r;
    float acc = rbo;
    for (int k = 0; k < 64; ++k) acc = fmaf(T1[row * 64 + k], Ws[k * 64 + col], acc);
    ha[r] = acc;
  }
  __syncthreads();
  #pragma unroll
  for (int r = 0; r < 8; ++r) T2[(rg * 8 + r) * 64 + col] = ha[r];
  for (int i = tid; i < 2048; i += 256) T1[i] = htkg[(size_t)rowbase * 64 + i];
  for (int i = tid; i < 8192; i += 256) Ws[i] = fc1W[i];
  __syncthreads();
  #pragma unroll
  for (int r = 0; r < 8; ++r) {
    const int row = rg * 8 + r;
    float acc = rf1b;
    for (int k = 0; k < 64; ++k) acc = fmaf(T1[row * 64 + k], Ws[k * 64 + col], acc);
    for (int k = 0; k < 64; ++k) acc = fmaf(T2[row * 64 + k], Ws[(64 + k) * 64 + col], acc);
    float y = fmaxf(acc, 0.f);
    float v = y * rf2;
    #pragma unroll
    for (int m = 32; m >= 1; m >>= 1) v += __shfl_xor(v, m);
    if (col == 0) pred[rowbase + row] = v + rf2b;
  }
}

extern "C" void kernel_launch(void* const* d_in, const int* in_sizes, int n_in,
                              void* d_out, int out_size, void* d_ws, size_t ws_size,
                              hipStream_t stream) {
  (void)in_sizes; (void)n_in; (void)out_size; (void)ws_size;
  const float* x       = (const float*)d_in[0];
  const int*   ei_t    = (const int*)d_in[1];
  const int*   ei_e    = (const int*)d_in[2];
  const float* gat1_W  = (const float*)d_in[3];
  const float* gat1_as = (const float*)d_in[4];
  const float* gat1_ad = (const float*)d_in[5];
  const float* gat1_b  = (const float*)d_in[6];
  const float* gat2_W  = (const float*)d_in[7];
  const float* gat2_as = (const float*)d_in[8];
  const float* gat2_ad = (const float*)d_in[9];
  const float* gat2_b  = (const float*)d_in[10];
  const float* gcn1_W  = (const float*)d_in[11];
  const float* gcn1_b  = (const float*)d_in[12];
  const float* gcn2_W  = (const float*)d_in[13];
  const float* gcn2_b  = (const float*)d_in[14];
  const float* Wq = (const float*)d_in[15]; const float* bq = (const float*)d_in[16];
  const float* Wk = (const float*)d_in[17]; const float* bk = (const float*)d_in[18];
  const float* Wv = (const float*)d_in[19]; const float* bv = (const float*)d_in[20];
  const float* Wo = (const float*)d_in[21]; const float* bo = (const float*)d_in[22];
  const float* fc1_W = (const float*)d_in[23]; const float* fc1_b = (const float*)d_in[24];
  const float* fc2_W = (const float*)d_in[25]; const float* fc2_b = (const float*)d_in[26];

  float* out  = (float*)d_out;
  float* attn = out + NN;   // [N, N] fp32, after pred[N]

  char* wsp = (char*)d_ws;
  size_t ofs = 0;
  auto take = [&](size_t bytes) -> char* {
    char* p = wsp + ofs;
    ofs = (ofs + bytes + 255) & ~(size_t)255;
    return p;
  };
  // ---- contiguous zero-init region first (single memset) ----
  int*   pos_t = (int*)take(NN * 4);
  int*   pos_e = (int*)take(NN * 4);
  float* a_s1  = (float*)take((size_t)NN * 2 * 4);
  float* a_d1  = (float*)take((size_t)NN * 2 * 4);
  float* a_s2  = (float*)take((size_t)NN * 4);
  float* a_d2  = (float*)take((size_t)NN * 4);
  float* a_l   = (float*)take((size_t)NN * 2 * 4);
  float* Obuf  = (float*)take((size_t)NN * 64 * 4);
  const size_t zero_span = ofs;
  // ---- rest ----
  int* off_t = (int*)take((NN + 1) * 4);
  int* off_e = (int*)take((NN + 1) * 4);
  int* src_t = (int*)take((size_t)ET * 4);
  int* src_e = (int*)take((size_t)ET * 4);
  float* h1    = (float*)take((size_t)NN * 128 * 4);
  float* g1out = (float*)take((size_t)NN * 128 * 4);
  float* h2    = (float*)take((size_t)NN * 64 * 4);
  float* htkg  = (float*)take((size_t)NN * 64 * 4);
  float* hg1   = (float*)take((size_t)NN * 64 * 4);
  float* h2g   = (float*)take((size_t)NN * 64 * 4);
  float* hekg  = (float*)take((size_t)NN * 64 * 4);
  unsigned short* qb = (unsigned short*)take((size_t)NN * 64 * 2);
  unsigned short* kb = (unsigned short*)take((size_t)NN * 64 * 2);
  unsigned short* Vt = (unsigned short*)take((size_t)64 * NN * 2);

  hipMemsetAsync(wsp, 0, zero_span, stream);

  // CSR for both graphs
  edge_hist2_k<<<2 * ET / 256, 256, 0, stream>>>(ei_t, ei_e, pos_t, pos_e);
  scan2_k<<<2, 1024, 0, stream>>>(pos_t, off_t, pos_e, off_e);
  edge_scatter2_k<<<2 * ET / 256, 256, 0, stream>>>(ei_t, ei_e, pos_t, pos_e, src_t, src_e);

  // x projections for both branches + gat1 att_sd epilogue
  mm_x_k<<<dim3(128, 6), 256, 0, stream>>>(x, gat1_W, gcn1_W, gat1_as, gat1_ad,
                                           h1, hg1, a_s1, a_d1);
  // merged gat1-agg + gcn1-agg+gemv
  agg1_k<<<NN + NN / 2, 128, 0, stream>>>(h1, a_s1, a_d1, off_t, src_t, gat1_b, g1out,
                                          hg1, off_e, src_e, gcn1_b, gcn2_W, h2g);
  // merged mm_gat2 + gcn_agg2
  mm2_k<<<256 + NN / 4, 256, 0, stream>>>(g1out, gat2_W, gat2_as, gat2_ad, h2, a_s2, a_d2,
                                          h2g, off_e, src_e, gcn2_b, hekg);
  // gat layer-2 aggregation
  gat_agg_k<1, 64><<<NN, 64, 0, stream>>>(h2, a_s2, a_d2, off_t, src_t, gat2_b, htkg, 64);

  // qkv projections + V transpose
  mm_qkv_k<<<dim3(128, 6), 256, 0, stream>>>(htkg, hekg, Wq, bq, Wk, bk, Wv, bv, qb, kb, Vt);

  // attention: q-block 128 x k-split 8, LDS-shared K/V tiles, swapped mfma + vec Esh
  att_lsum_k<<<dim3(64, 8), 512, 0, stream>>>(qb, kb, a_l);
  att_pv_k<<<dim3(64, 8), 512, 0, stream>>>(qb, kb, Vt, a_l, attn, Obuf);

  // fused epilogue: Wo + fc1 + fc2
  tail_k<<<256, 256, 0, stream>>>(Obuf, htkg, Wo, bo, fc1_W, fc1_b, fc2_W, fc2_b, out);
}

// Round 9
// 564.514 us; speedup vs baseline: 1.0784x; 1.0657x over previous
//
#include <hip/hip_runtime.h>
#include <cstdint>
#include <cstddef>

#define NN 8192
#define EE 262144
#define ET 270336   // EE + NN self loops

using short8  = __attribute__((ext_vector_type(8))) short;
using floatx4 = __attribute__((ext_vector_type(4))) float;

__device__ __forceinline__ unsigned short f2bf(float f) {
  unsigned int u = __float_as_uint(f);
  u += 0x7fffu + ((u >> 16) & 1u);          // RNE
  return (unsigned short)(u >> 16);
}

// ---------------- CSR build, both graphs in one launch ----------------
__global__ void edge_hist2_k(const int* __restrict__ ei_t, const int* __restrict__ ei_e,
                             int* __restrict__ cnt_t, int* __restrict__ cnt_e) {
  int idx = blockIdx.x * 256 + threadIdx.x;
  int g = idx >= ET;                        // block-uniform (ET % 256 == 0)
  int e = g ? idx - ET : idx;
  const int* ei = g ? ei_e : ei_t;
  int* cnt = g ? cnt_e : cnt_t;
  int d = (e < EE) ? ei[EE + e] : (e - EE);
  atomicAdd(&cnt[d], 1);
}

__global__ void scan2_k(int* cnt_t, int* off_t, int* cnt_e, int* off_e) {
  int* cnt = blockIdx.x ? cnt_e : cnt_t;    // pos aliases cnt (overwritten)
  int* off = blockIdx.x ? off_e : off_t;
  __shared__ int s[1024];
  int t = threadIdx.x;
  int v[8]; int base = t * 8; int sum = 0;
  #pragma unroll
  for (int j = 0; j < 8; ++j) { v[j] = cnt[base + j]; sum += v[j]; }
  s[t] = sum; __syncthreads();
  for (int o = 1; o < 1024; o <<= 1) {
    int x = (t >= o) ? s[t - o] : 0;
    __syncthreads();
    s[t] += x;
    __syncthreads();
  }
  int excl = s[t] - sum;
  #pragma unroll
  for (int j = 0; j < 8; ++j) { off[base + j] = excl; cnt[base + j] = excl; excl += v[j]; }
  if (t == 1023) off[NN] = excl;
}

__global__ void edge_scatter2_k(const int* __restrict__ ei_t, const int* __restrict__ ei_e,
                                int* __restrict__ pos_t, int* __restrict__ pos_e,
                                int* __restrict__ srcs_t, int* __restrict__ srcs_e) {
  int idx = blockIdx.x * 256 + threadIdx.x;
  int g = idx >= ET;
  int e = g ? idx - ET : idx;
  const int* ei = g ? ei_e : ei_t;
  int* pos = g ? pos_e : pos_t;
  int* srcs = g ? srcs_e : srcs_t;
  int sv, d;
  if (e < EE) { sv = ei[e]; d = ei[EE + e]; } else { sv = d = e - EE; }
  int p = atomicAdd(&pos[d], 1);
  srcs[p] = sv;
}

// ---------------- shared GEMM inner loop ----------------
__device__ __forceinline__ void gemm_core(const float* __restrict__ A, int lda, int K,
                                          const float* __restrict__ Bs, int row0, int col,
                                          float acc[8]) {
  #pragma unroll
  for (int r = 0; r < 8; ++r) acc[r] = 0.f;
  for (int k = 0; k < K; k += 4) {
    float b0 = Bs[(k + 0) * 32 + col], b1 = Bs[(k + 1) * 32 + col];
    float b2 = Bs[(k + 2) * 32 + col], b3 = Bs[(k + 3) * 32 + col];
    #pragma unroll
    for (int r = 0; r < 8; ++r) {
      const float4 a4 = *(const float4*)(A + (size_t)(row0 + r) * lda + k);
      acc[r] = fmaf(a4.x, b0, acc[r]);
      acc[r] = fmaf(a4.y, b1, acc[r]);
      acc[r] = fmaf(a4.z, b2, acc[r]);
      acc[r] = fmaf(a4.w, b3, acc[r]);
    }
  }
}

// ---------------- mm_x: h1 = x@gat1_W (+att_sd epilogue), hg1 = x@gcn1_W ----------------
__global__ __launch_bounds__(256) void mm_x_k(const float* __restrict__ x,
    const float* __restrict__ Wgat, const float* __restrict__ Wgcn,
    const float* __restrict__ as_w, const float* __restrict__ ad_w,
    float* __restrict__ h1, float* __restrict__ hg1,
    float* __restrict__ a_s1, float* __restrict__ a_d1) {
  __shared__ float Bs[256 * 32];
  const int tid = threadIdx.x, by = blockIdx.y;
  const bool gat = by < 4;
  const int NC = gat ? 128 : 64;
  const int c0 = gat ? by * 32 : (by - 4) * 32;
  const float* B = gat ? Wgat : Wgcn;
  for (int idx = tid; idx < 256 * 32; idx += 256)
    Bs[idx] = B[(idx >> 5) * NC + c0 + (idx & 31)];
  __syncthreads();
  const int row0 = blockIdx.x * 64 + (tid >> 5) * 8;
  const int col = tid & 31;
  float acc[8];
  gemm_core(x, 256, 256, Bs, row0, col, acc);
  if (gat) {
    #pragma unroll
    for (int r = 0; r < 8; ++r) h1[(size_t)(row0 + r) * 128 + c0 + col] = acc[r];
    const int head = c0 >> 6;
    const float asw = as_w[head * 64 + (c0 & 63) + col];
    const float adw = ad_w[head * 64 + (c0 & 63) + col];
    float ps[8], pd[8];
    #pragma unroll
    for (int r = 0; r < 8; ++r) { ps[r] = acc[r] * asw; pd[r] = acc[r] * adw; }
    #pragma unroll
    for (int m = 16; m >= 1; m >>= 1)
      #pragma unroll
      for (int r = 0; r < 8; ++r) { ps[r] += __shfl_xor(ps[r], m); pd[r] += __shfl_xor(pd[r], m); }
    if (col == 0) {
      #pragma unroll
      for (int r = 0; r < 8; ++r) {
        atomicAdd(&a_s1[(row0 + r) * 2 + head], ps[r]);
        atomicAdd(&a_d1[(row0 + r) * 2 + head], pd[r]);
      }
    }
  } else {
    #pragma unroll
    for (int r = 0; r < 8; ++r) hg1[(size_t)(row0 + r) * 64 + c0 + col] = acc[r];
  }
}

// ---------------- GAT aggregation ----------------
template<int H, int C>
__device__ __forceinline__ void gat_agg_body(const float* __restrict__ h,
    const float* __restrict__ a_s, const float* __restrict__ a_d,
    const int* __restrict__ off, const int* __restrict__ srcs,
    const float* __restrict__ bias, float* __restrict__ out, int ldout, int b) {
  constexpr int HC = H * C;
  const int tid = threadIdx.x;
  const int hd = tid / C;
  const int r0 = off[b], r1 = off[b + 1];
  __shared__ int s_src[HC];
  __shared__ float s_w[HC][H];
  float ad[H];
  #pragma unroll
  for (int hh = 0; hh < H; ++hh) ad[hh] = a_d[b * H + hh];
  float acc = 0.f, den = 0.f;
  for (int base = r0; base < r1; base += HC) {
    const int cnt = min(HC, r1 - base);
    const int cnt4 = (cnt + 3) & ~3;
    __syncthreads();
    int e = base + tid;
    if (e < r1) {
      int sv = srcs[e];
      s_src[tid] = sv;
      #pragma unroll
      for (int hh = 0; hh < H; ++hh) {
        float xv = a_s[sv * H + hh] + ad[hh];
        xv = xv > 0.f ? xv : 0.2f * xv;     // leaky_relu 0.2
        s_w[tid][hh] = __expf(xv);
      }
    } else if (tid < cnt4) {                // zero-weight padding
      s_src[tid] = 0;
      #pragma unroll
      for (int hh = 0; hh < H; ++hh) s_w[tid][hh] = 0.f;
    }
    __syncthreads();
    for (int j = 0; j < cnt4; j += 4) {
      #pragma unroll
      for (int u = 0; u < 4; ++u) {
        float wv = s_w[j + u][hd];
        den += wv;
        acc = fmaf(wv, h[(size_t)s_src[j + u] * HC + tid], acc);
      }
    }
  }
  float o = acc / den + bias[tid];
  out[(size_t)b * ldout + tid] = o > 0.f ? o : (__expf(o) - 1.f);  // elu
}

template<int H, int C>
__global__ void gat_agg_k(const float* __restrict__ h, const float* __restrict__ a_s,
                          const float* __restrict__ a_d, const int* __restrict__ off,
                          const int* __restrict__ srcs, const float* __restrict__ bias,
                          float* __restrict__ out, int ldout) {
  gat_agg_body<H, C>(h, a_s, a_d, off, srcs, bias, out, ldout, blockIdx.x);
}

// ---------------- merged: gat1 aggregation (blocks 0..NN) + gcn1 agg+gemv (2 nodes/blk) ----
__global__ __launch_bounds__(128) void agg1_k(
    const float* __restrict__ h1, const float* __restrict__ a_s1, const float* __restrict__ a_d1,
    const int* __restrict__ off_t, const int* __restrict__ src_t,
    const float* __restrict__ gat1_b, float* __restrict__ g1out,
    const float* __restrict__ hg1, const int* __restrict__ off_e, const int* __restrict__ src_e,
    const float* __restrict__ gcn1_b, const float* __restrict__ gcn2_W, float* __restrict__ h2g) {
  const int tid = threadIdx.x;
  if (blockIdx.x < NN) {
    gat_agg_body<2, 64>(h1, a_s1, a_d1, off_t, src_t, gat1_b, g1out, 128, blockIdx.x);
  } else {
    const int nb = (blockIdx.x - NN) * 2;
    const int sub = tid >> 6, t = tid & 63;
    const int node = nb + sub;
    __shared__ int s_src2[2][64];
    __shared__ float s_nrm2[2][64];
    __shared__ float s_row2[2][64];
    const int r0 = off_e[node], r1 = off_e[node + 1];
    const int cA = off_e[nb + 1] - off_e[nb];
    const int cB = off_e[nb + 2] - off_e[nb + 1];
    const int trips = (max(cA, cB) + 63) >> 6;
    float dinv_b = rsqrtf((float)max(r1 - r0, 1));
    float acc = 0.f;
    for (int it = 0; it < trips; ++it) {
      const int cnt = min(64, r1 - (r0 + it * 64));
      const int cnt4 = (cnt + 3) & ~3;
      __syncthreads();
      int e = r0 + it * 64 + t;
      if (e < r1) {
        int sv = src_e[e];
        s_src2[sub][t] = sv;
        int ds = off_e[sv + 1] - off_e[sv];
        s_nrm2[sub][t] = dinv_b * rsqrtf((float)max(ds, 1));
      } else if (t < cnt4) {
        s_src2[sub][t] = 0;
        s_nrm2[sub][t] = 0.f;
      }
      __syncthreads();
      for (int j = 0; j < cnt4; j += 4) {
        #pragma unroll
        for (int u = 0; u < 4; ++u)
          acc = fmaf(s_nrm2[sub][j + u], hg1[(size_t)s_src2[sub][j + u] * 64 + t], acc);
      }
    }
    s_row2[sub][t] = fmaxf(acc + gcn1_b[t], 0.f);
    __syncthreads();
    float acc2 = 0.f;
    for (int k = 0; k < 64; ++k)
      acc2 = fmaf(s_row2[sub][k], gcn2_W[k * 64 + t], acc2);
    h2g[(size_t)node * 64 + t] = acc2;
  }
}

// ---------------- merged: mm_gat2 (blocks 0..256) + gcn_agg2 (4 nodes/blk) ----------------
__global__ __launch_bounds__(256) void mm2_k(
    const float* __restrict__ g1out, const float* __restrict__ gat2_W,
    const float* __restrict__ gat2_as, const float* __restrict__ gat2_ad,
    float* __restrict__ h2, float* __restrict__ a_s2, float* __restrict__ a_d2,
    const float* __restrict__ h2g, const int* __restrict__ off_e, const int* __restrict__ src_e,
    const float* __restrict__ gcn2_b, float* __restrict__ hekg) {
  const int tid = threadIdx.x;
  if (blockIdx.x < 256) {
    __shared__ float Bs[128 * 32];
    const int bx = blockIdx.x & 127;
    const int c0 = (blockIdx.x >> 7) * 32;
    for (int idx = tid; idx < 128 * 32; idx += 256)
      Bs[idx] = gat2_W[(idx >> 5) * 64 + c0 + (idx & 31)];
    __syncthreads();
    const int row0 = bx * 64 + (tid >> 5) * 8;
    const int col = tid & 31;
    float acc[8];
    gemm_core(g1out, 128, 128, Bs, row0, col, acc);
    const float asw = gat2_as[c0 + col];
    const float adw = gat2_ad[c0 + col];
    float ps[8], pd[8];
    #pragma unroll
    for (int r = 0; r < 8; ++r) {
      h2[(size_t)(row0 + r) * 64 + c0 + col] = acc[r];
      ps[r] = acc[r] * asw; pd[r] = acc[r] * adw;
    }
    #pragma unroll
    for (int m = 16; m >= 1; m >>= 1)
      #pragma unroll
      for (int r = 0; r < 8; ++r) { ps[r] += __shfl_xor(ps[r], m); pd[r] += __shfl_xor(pd[r], m); }
    if (col == 0) {
      #pragma unroll
      for (int r = 0; r < 8; ++r) {
        atomicAdd(&a_s2[row0 + r], ps[r]);
        atomicAdd(&a_d2[row0 + r], pd[r]);
      }
    }
  } else {
    const int nb = (blockIdx.x - 256) * 4;
    const int sub = tid >> 6, t = tid & 63;
    const int node = nb + sub;
    __shared__ int s_src4[4][64];
    __shared__ float s_nrm4[4][64];
    const int r0 = off_e[node], r1 = off_e[node + 1];
    int cmax = 0;
    #pragma unroll
    for (int i = 0; i < 4; ++i) cmax = max(cmax, off_e[nb + i + 1] - off_e[nb + i]);
    const int trips = (cmax + 63) >> 6;
    float dinv_b = rsqrtf((float)max(r1 - r0, 1));
    float acc = 0.f;
    for (int it = 0; it < trips; ++it) {
      const int cnt = min(64, r1 - (r0 + it * 64));
      const int cnt4 = (cnt + 3) & ~3;
      __syncthreads();
      int e = r0 + it * 64 + t;
      if (e < r1) {
        int sv = src_e[e];
        s_src4[sub][t] = sv;
        int ds = off_e[sv + 1] - off_e[sv];
        s_nrm4[sub][t] = dinv_b * rsqrtf((float)max(ds, 1));
      } else if (t < cnt4) {
        s_src4[sub][t] = 0;
        s_nrm4[sub][t] = 0.f;
      }
      __syncthreads();
      for (int j = 0; j < cnt4; j += 4) {
        #pragma unroll
        for (int u = 0; u < 4; ++u)
          acc = fmaf(s_nrm4[sub][j + u], h2g[(size_t)s_src4[sub][j + u] * 64 + t], acc);
      }
    }
    hekg[(size_t)node * 64 + t] = fmaxf(acc + gcn2_b[t], 0.f);
  }
}

// ---------------- qkv projections (+V transpose) ----------------
__global__ __launch_bounds__(256) void mm_qkv_k(const float* __restrict__ htkg,
    const float* __restrict__ hekg,
    const float* __restrict__ Wq, const float* __restrict__ bq,
    const float* __restrict__ Wk, const float* __restrict__ bk,
    const float* __restrict__ Wv, const float* __restrict__ bv,
    unsigned short* __restrict__ qb, unsigned short* __restrict__ kb,
    unsigned short* __restrict__ Vt) {
  __shared__ float Bs[64 * 32];
  __shared__ float Ts[32][65];
  const int tid = threadIdx.x, by = blockIdx.y;
  const int kind = by >> 1;
  const int c0 = (by & 1) * 32;
  const float* A = (kind == 0) ? htkg : hekg;
  const float* B = (kind == 0) ? Wq : (kind == 1) ? Wk : Wv;
  const float* bias = (kind == 0) ? bq : (kind == 1) ? bk : bv;
  for (int idx = tid; idx < 64 * 32; idx += 256)
    Bs[idx] = B[(idx >> 5) * 64 + c0 + (idx & 31)];
  __syncthreads();
  const int row0 = blockIdx.x * 64 + (tid >> 5) * 8;
  const int col = tid & 31;
  float acc[8];
  gemm_core(A, 64, 64, Bs, row0, col, acc);
  const float bb = bias[c0 + col];
  if (kind == 0) {
    const float SCL = 0.17677669529663687f * 1.4426950408889634f;  // 1/sqrt(32) * log2(e)
    #pragma unroll
    for (int r = 0; r < 8; ++r)
      qb[(size_t)(row0 + r) * 64 + c0 + col] = f2bf((acc[r] + bb) * SCL);
  } else if (kind == 1) {
    #pragma unroll
    for (int r = 0; r < 8; ++r)
      kb[(size_t)(row0 + r) * 64 + c0 + col] = f2bf(acc[r] + bb);
  } else {
    const int rl = (tid >> 5) * 8;
    #pragma unroll
    for (int r = 0; r < 8; ++r) Ts[col][rl + r] = acc[r] + bb;
    __syncthreads();
    const int c = tid >> 3, rr = (tid & 7) * 8;
    short8 pk;
    #pragma unroll
    for (int j = 0; j < 8; ++j) pk[j] = (short)f2bf(Ts[c][rr + j]);
    *(short8*)(Vt + (size_t)(c0 + c) * NN + blockIdx.x * 64 + rr) = pk;
  }
}

// ---------------- attention pass 1: softmax denominators (swapped mfma) ----------------
// grid (64,8), 512 thr (8 waves; 16 q-rows each). Block = 128 q-rows x 1024-key split.
// S^T = mfma(K, Q): lane (ql,quad) holds S[q0+ql][...] -> row sum lane-local +
// 2-step quad reduce. Verified correct (absmax-identical) in rounds 6 and 8.
__global__ __launch_bounds__(512) void att_lsum_k(
    const unsigned short* __restrict__ qb, const unsigned short* __restrict__ kb,
    float* __restrict__ lsum) {
  __shared__ __align__(16) short Kbuf[2][64 * 64];
  const int tid = threadIdx.x;
  const int lane = tid & 63, wv = tid >> 6;
  const int ql = lane & 15, quad = lane >> 4;
  const int q0 = blockIdx.x * 128 + wv * 16;
  const int k0 = blockIdx.y * 1024;
  const floatx4 zf = {0.f, 0.f, 0.f, 0.f};

  short8 qf[2];
  #pragma unroll
  for (int h = 0; h < 2; ++h)
    qf[h] = *(const short8*)(qb + (size_t)(q0 + ql) * 64 + h * 32 + quad * 8);

  const int sr = tid >> 3, sc = tid & 7;     // staging: row sr (0..63), colblk sc
  const int swc = (sc ^ (sr & 7)) * 8;
  short8 krg;

  float lacc[2] = {0.f, 0.f};

  // prologue: stage tile 0
  {
    krg = *(const short8*)(kb + (size_t)(k0 + sr) * 64 + sc * 8);
    *(short8*)&Kbuf[0][sr * 64 + swc] = krg;
  }
  __syncthreads();

  for (int t = 0; t < 16; ++t) {
    if (t < 15)
      krg = *(const short8*)(kb + (size_t)(k0 + (t + 1) * 64 + sr) * 64 + sc * 8);
    const short* Kc = Kbuf[t & 1];
    #pragma unroll
    for (int kt = 0; kt < 4; ++kt) {
      const int row = kt * 16 + ql;
      short8 kf[2];
      #pragma unroll
      for (int h = 0; h < 2; ++h)
        kf[h] = *(const short8*)&Kc[row * 64 + ((h * 4 + quad) ^ (row & 7)) * 8];
      #pragma unroll
      for (int h = 0; h < 2; ++h) {
        floatx4 s = __builtin_amdgcn_mfma_f32_16x16x32_bf16(kf[h], qf[h], zf, 0, 0, 0);
        #pragma unroll
        for (int r = 0; r < 4; ++r) lacc[h] += __builtin_amdgcn_exp2f(s[r]);
      }
    }
    if (t < 15)
      *(short8*)&Kbuf[(t + 1) & 1][sr * 64 + swc] = krg;
    __syncthreads();
  }

  #pragma unroll
  for (int h = 0; h < 2; ++h) {
    lacc[h] += __shfl_xor(lacc[h], 16);
    lacc[h] += __shfl_xor(lacc[h], 32);
  }
  if (lane < 16) {
    #pragma unroll
    for (int h = 0; h < 2; ++h)
      atomicAdd(&lsum[(q0 + ql) * 2 + h], lacc[h]);
  }
}

// ---------------- attention pass 2: P/attn/PV with LDS-shared K/V tiles ----------------
// REVERTED to the round-5 (578.4 us) version: forward mfma(Q,K), scalar C-layout->Esh
// writes (2-way-free bank pattern), b128 fragment reads, register attn writes that
// complete full 256-B lines per t-iteration. The swapped variants (r6 shfl, r8 vec-Esh)
// both measured ~25 us slower despite fewer issue slots — structure banked as best.
__global__ __launch_bounds__(512, 4) void att_pv_k(
    const unsigned short* __restrict__ qb, const unsigned short* __restrict__ kb,
    const unsigned short* __restrict__ Vt, const float* __restrict__ lsum,
    float* __restrict__ attn, float* __restrict__ O) {
  __shared__ __align__(16) short Kbuf[2][64 * 64];
  __shared__ __align__(16) short Vbuf[2][64 * 64];
  __shared__ __align__(16) float Esh[8][2][16 * 36];
  const int tid = threadIdx.x;
  const int lane = tid & 63, wv = tid >> 6;
  const int ql = lane & 15, quad = lane >> 4;
  const int q0 = blockIdx.x * 128 + wv * 16;
  const int k0 = blockIdx.y * 1024;
  const floatx4 zf = {0.f, 0.f, 0.f, 0.f};

  short8 qf[2];
  #pragma unroll
  for (int h = 0; h < 2; ++h)
    qf[h] = *(const short8*)(qb + (size_t)(q0 + ql) * 64 + h * 32 + quad * 8);

  float invl[2][4];
  #pragma unroll
  for (int h = 0; h < 2; ++h)
    #pragma unroll
    for (int r = 0; r < 4; ++r)
      invl[h][r] = 1.0f / lsum[(q0 + quad * 4 + r) * 2 + h];

  const int sr = tid >> 3, sc = tid & 7;   // staging row (0..63), colblk (0..7)
  const int swc = (sc ^ (sr & 7)) * 8;
  short8 krg, vrg;

  floatx4 oacc[2][2];
  #pragma unroll
  for (int h = 0; h < 2; ++h)
    #pragma unroll
    for (int hf = 0; hf < 2; ++hf) oacc[h][hf] = zf;

  // prologue: stage tile 0
  {
    krg = *(const short8*)(kb + (size_t)(k0 + sr) * 64 + sc * 8);
    vrg = *(const short8*)(Vt + (size_t)sr * NN + k0 + sc * 8);
    *(short8*)&Kbuf[0][sr * 64 + swc] = krg;
    *(short8*)&Vbuf[0][sr * 64 + swc] = vrg;
  }
  __syncthreads();

  for (int t = 0; t < 16; ++t) {
    if (t < 15) {
      krg = *(const short8*)(kb + (size_t)(k0 + (t + 1) * 64 + sr) * 64 + sc * 8);
      vrg = *(const short8*)(Vt + (size_t)sr * NN + k0 + (t + 1) * 64 + sc * 8);
    }
    const short* Kc = Kbuf[t & 1];
    const short* Vc = Vbuf[t & 1];
    #pragma unroll
    for (int ks = 0; ks < 2; ++ks) {
      short8 kf[2][2], vf[2][2];
      #pragma unroll
      for (int kt = 0; kt < 2; ++kt) {
        const int row = ks * 32 + kt * 16 + ql;
        #pragma unroll
        for (int h = 0; h < 2; ++h)
          kf[kt][h] = *(const short8*)&Kc[row * 64 + ((h * 4 + quad) ^ (row & 7)) * 8];
      }
      #pragma unroll
      for (int h = 0; h < 2; ++h)
        #pragma unroll
        for (int hf = 0; hf < 2; ++hf) {
          const int d = h * 32 + hf * 16 + ql;
          vf[h][hf] = *(const short8*)&Vc[d * 64 + ((ks * 4 + quad) ^ (d & 7)) * 8];
        }

      floatx4 p[2][2];  // [head][kt]
      #pragma unroll
      for (int h = 0; h < 2; ++h)
        #pragma unroll
        for (int kt = 0; kt < 2; ++kt) {
          floatx4 s = __builtin_amdgcn_mfma_f32_16x16x32_bf16(qf[h], kf[kt][h], zf, 0, 0, 0);
          #pragma unroll
          for (int r = 0; r < 4; ++r)
            p[h][kt][r] = __builtin_amdgcn_exp2f(s[r]) * invl[h][r];
        }
      // attn head-mean straight from registers (line completes within sub-step)
      #pragma unroll
      for (int kt = 0; kt < 2; ++kt)
        #pragma unroll
        for (int r = 0; r < 4; ++r)
          attn[(size_t)(q0 + quad * 4 + r) * NN + k0 + t * 64 + ks * 32 + kt * 16 + ql] =
              0.5f * (p[0][kt][r] + p[1][kt][r]);
      // C-layout -> LDS -> A-layout, PV mfma
      #pragma unroll
      for (int h = 0; h < 2; ++h)
        #pragma unroll
        for (int kt = 0; kt < 2; ++kt)
          #pragma unroll
          for (int r = 0; r < 4; ++r)
            Esh[wv][h][(quad * 4 + r) * 36 + kt * 16 + ql] = p[h][kt][r];
      #pragma unroll
      for (int h = 0; h < 2; ++h) {
        const float* ep = &Esh[wv][h][ql * 36 + quad * 8];
        float4 x0 = *(const float4*)ep;
        float4 x1 = *(const float4*)(ep + 4);
        short8 ef;
        ef[0] = (short)f2bf(x0.x); ef[1] = (short)f2bf(x0.y);
        ef[2] = (short)f2bf(x0.z); ef[3] = (short)f2bf(x0.w);
        ef[4] = (short)f2bf(x1.x); ef[5] = (short)f2bf(x1.y);
        ef[6] = (short)f2bf(x1.z); ef[7] = (short)f2bf(x1.w);
        #pragma unroll
        for (int hf = 0; hf < 2; ++hf)
          oacc[h][hf] = __builtin_amdgcn_mfma_f32_16x16x32_bf16(ef, vf[h][hf], oacc[h][hf], 0, 0, 0);
      }
    }
    if (t < 15) {
      *(short8*)&Kbuf[(t + 1) & 1][sr * 64 + swc] = krg;
      *(short8*)&Vbuf[(t + 1) & 1][sr * 64 + swc] = vrg;
    }
    __syncthreads();
  }

  #pragma unroll
  for (int h = 0; h < 2; ++h)
    #pragma unroll
    for (int hf = 0; hf < 2; ++hf)
      #pragma unroll
      for (int r = 0; r < 4; ++r)
        atomicAdd(&O[(size_t)(q0 + quad * 4 + r) * 64 + h * 32 + hf * 16 + ql], oacc[h][hf][r]);
}

// ---------------- tail: h_attn=O@Wo+bo ; y1=relu([htkg|h_attn]@fc1+b) ; pred=y1@fc2+b ----
__global__ __launch_bounds__(256) void tail_k(const float* __restrict__ O,
    const float* __restrict__ htkg, const float* __restrict__ Wo, const float* __restrict__ bo,
    const float* __restrict__ fc1W, const float* __restrict__ fc1b,
    const float* __restrict__ fc2W, const float* __restrict__ fc2b,
    float* __restrict__ pred) {
  __shared__ float Ws[8192];
  __shared__ float T1[2048];
  __shared__ float T2[2048];
  const int tid = threadIdx.x;
  const int col = tid & 63, rg = tid >> 6;
  const int rowbase = blockIdx.x * 32;
  for (int i = tid; i < 2048; i += 256) T1[i] = O[(size_t)rowbase * 64 + i];
  for (int i = tid; i < 4096; i += 256) Ws[i] = Wo[i];
  const float rbo = bo[col], rf1b = fc1b[col], rf2 = fc2W[col], rf2b = fc2b[0];
  __syncthreads();
  float ha[8];
  #pragma unroll
  for (int r = 0; r < 8; ++r) {
    const int row = rg * 8 + r;
    float acc = rbo;
    for (int k = 0; k < 64; ++k) acc = fmaf(T1[row * 64 + k], Ws[k * 64 + col], acc);
    ha[r] = acc;
  }
  __syncthreads();
  #pragma unroll
  for (int r = 0; r < 8; ++r) T2[(rg * 8 + r) * 64 + col] = ha[r];
  for (int i = tid; i < 2048; i += 256) T1[i] = htkg[(size_t)rowbase * 64 + i];
  for (int i = tid; i < 8192; i += 256) Ws[i] = fc1W[i];
  __syncthreads();
  #pragma unroll
  for (int r = 0; r < 8; ++r) {
    const int row = rg * 8 + r;
    float acc = rf1b;
    for (int k = 0; k < 64; ++k) acc = fmaf(T1[row * 64 + k], Ws[k * 64 + col], acc);
    for (int k = 0; k < 64; ++k) acc = fmaf(T2[row * 64 + k], Ws[(64 + k) * 64 + col], acc);
    float y = fmaxf(acc, 0.f);
    float v = y * rf2;
    #pragma unroll
    for (int m = 32; m >= 1; m >>= 1) v += __shfl_xor(v, m);
    if (col == 0) pred[rowbase + row] = v + rf2b;
  }
}

extern "C" void kernel_launch(void* const* d_in, const int* in_sizes, int n_in,
                              void* d_out, int out_size, void* d_ws, size_t ws_size,
                              hipStream_t stream) {
  (void)in_sizes; (void)n_in; (void)out_size; (void)ws_size;
  const float* x       = (const float*)d_in[0];
  const int*   ei_t    = (const int*)d_in[1];
  const int*   ei_e    = (const int*)d_in[2];
  const float* gat1_W  = (const float*)d_in[3];
  const float* gat1_as = (const float*)d_in[4];
  const float* gat1_ad = (const float*)d_in[5];
  const float* gat1_b  = (const float*)d_in[6];
  const float* gat2_W  = (const float*)d_in[7];
  const float* gat2_as = (const float*)d_in[8];
  const float* gat2_ad = (const float*)d_in[9];
  const float* gat2_b  = (const float*)d_in[10];
  const float* gcn1_W  = (const float*)d_in[11];
  const float* gcn1_b  = (const float*)d_in[12];
  const float* gcn2_W  = (const float*)d_in[13];
  const float* gcn2_b  = (const float*)d_in[14];
  const float* Wq = (const float*)d_in[15]; const float* bq = (const float*)d_in[16];
  const float* Wk = (const float*)d_in[17]; const float* bk = (const float*)d_in[18];
  const float* Wv = (const float*)d_in[19]; const float* bv = (const float*)d_in[20];
  const float* Wo = (const float*)d_in[21]; const float* bo = (const float*)d_in[22];
  const float* fc1_W = (const float*)d_in[23]; const float* fc1_b = (const float*)d_in[24];
  const float* fc2_W = (const float*)d_in[25]; const float* fc2_b = (const float*)d_in[26];

  float* out  = (float*)d_out;
  float* attn = out + NN;   // [N, N] fp32, after pred[N]

  char* wsp = (char*)d_ws;
  size_t ofs = 0;
  auto take = [&](size_t bytes) -> char* {
    char* p = wsp + ofs;
    ofs = (ofs + bytes + 255) & ~(size_t)255;
    return p;
  };
  // ---- contiguous zero-init region first (single memset) ----
  int*   pos_t = (int*)take(NN * 4);
  int*   pos_e = (int*)take(NN * 4);
  float* a_s1  = (float*)take((size_t)NN * 2 * 4);
  float* a_d1  = (float*)take((size_t)NN * 2 * 4);
  float* a_s2  = (float*)take((size_t)NN * 4);
  float* a_d2  = (float*)take((size_t)NN * 4);
  float* a_l   = (float*)take((size_t)NN * 2 * 4);
  float* Obuf  = (float*)take((size_t)NN * 64 * 4);
  const size_t zero_span = ofs;
  // ---- rest ----
  int* off_t = (int*)take((NN + 1) * 4);
  int* off_e = (int*)take((NN + 1) * 4);
  int* src_t = (int*)take((size_t)ET * 4);
  int* src_e = (int*)take((size_t)ET * 4);
  float* h1    = (float*)take((size_t)NN * 128 * 4);
  float* g1out = (float*)take((size_t)NN * 128 * 4);
  float* h2    = (float*)take((size_t)NN * 64 * 4);
  float* htkg  = (float*)take((size_t)NN * 64 * 4);
  float* hg1   = (float*)take((size_t)NN * 64 * 4);
  float* h2g   = (float*)take((size_t)NN * 64 * 4);
  float* hekg  = (float*)take((size_t)NN * 64 * 4);
  unsigned short* qb = (unsigned short*)take((size_t)NN * 64 * 2);
  unsigned short* kb = (unsigned short*)take((size_t)NN * 64 * 2);
  unsigned short* Vt = (unsigned short*)take((size_t)64 * NN * 2);

  hipMemsetAsync(wsp, 0, zero_span, stream);

  // CSR for both graphs
  edge_hist2_k<<<2 * ET / 256, 256, 0, stream>>>(ei_t, ei_e, pos_t, pos_e);
  scan2_k<<<2, 1024, 0, stream>>>(pos_t, off_t, pos_e, off_e);
  edge_scatter2_k<<<2 * ET / 256, 256, 0, stream>>>(ei_t, ei_e, pos_t, pos_e, src_t, src_e);

  // x projections for both branches + gat1 att_sd epilogue
  mm_x_k<<<dim3(128, 6), 256, 0, stream>>>(x, gat1_W, gcn1_W, gat1_as, gat1_ad,
                                           h1, hg1, a_s1, a_d1);
  // merged gat1-agg + gcn1-agg+gemv
  agg1_k<<<NN + NN / 2, 128, 0, stream>>>(h1, a_s1, a_d1, off_t, src_t, gat1_b, g1out,
                                          hg1, off_e, src_e, gcn1_b, gcn2_W, h2g);
  // merged mm_gat2 + gcn_agg2
  mm2_k<<<256 + NN / 4, 256, 0, stream>>>(g1out, gat2_W, gat2_as, gat2_ad, h2, a_s2, a_d2,
                                          h2g, off_e, src_e, gcn2_b, hekg);
  // gat layer-2 aggregation
  gat_agg_k<1, 64><<<NN, 64, 0, stream>>>(h2, a_s2, a_d2, off_t, src_t, gat2_b, htkg, 64);

  // qkv projections + V transpose
  mm_qkv_k<<<dim3(128, 6), 256, 0, stream>>>(htkg, hekg, Wq, bq, Wk, bk, Wv, bv, qb, kb, Vt);

  // attention: q-block 128 x k-split 8, LDS-shared K/V tiles
  att_lsum_k<<<dim3(64, 8), 512, 0, stream>>>(qb, kb, a_l);
  att_pv_k<<<dim3(64, 8), 512, 0, stream>>>(qb, kb, Vt, a_l, attn, Obuf);

  // fused epilogue: Wo + fc1 + fc2
  tail_k<<<256, 256, 0, stream>>>(Obuf, htkg, Wo, bo, fc1_W, fc1_b, fc2_W, fc2_b, out);
}